// Round 3
// baseline (778.413 us; speedup 1.0000x reference)
//
#include <hip/hip_runtime.h>
#include <cstdint>

#define NB 8
#define NC 96
#define NC2 192
#define NPT 3136    // 56*56
#define NK 9
#define RST 104     // fnT row stride in floats (96 fn + sq at [96] + pad), 416B = 26 float4
#define JSPLIT 28
#define JTASK 112   // 3136/28
static constexpr float BN_EPS = 1e-5f;
typedef unsigned long long u64;

// ---------------- K1: fold BN into weights, build fused weight layouts ----------------
__global__ void k_fuse(const float* __restrict__ W1, const float* __restrict__ b1,
                       const float* __restrict__ g1, const float* __restrict__ be1,
                       const float* __restrict__ m1, const float* __restrict__ v1,
                       const float* __restrict__ Wg,
                       const float* __restrict__ W2, const float* __restrict__ b2,
                       const float* __restrict__ g2, const float* __restrict__ be2,
                       const float* __restrict__ m2, const float* __restrict__ v2,
                       float* __restrict__ W1f, float* __restrict__ b1f,
                       float* __restrict__ Wuv,
                       float* __restrict__ W2f, float* __restrict__ b2f) {
  int t = blockIdx.x * blockDim.x + threadIdx.x;
  int nth = gridDim.x * blockDim.x;
  for (int i = t; i < NC * NC; i += nth) {
    int c = i / NC, o = i % NC;
    float inv = g1[o] / sqrtf(v1[o] + BN_EPS);
    W1f[i] = W1[o * NC + c] * inv;
  }
  for (int o = t; o < NC; o += nth) {
    float inv = g1[o] / sqrtf(v1[o] + BN_EPS);
    b1f[o] = b1[o] * inv + be1[o] - m1[o] * inv;
    float inv2v = g2[o] / sqrtf(v2[o] + BN_EPS);
    b2f[o] = b2[o] * inv2v + be2[o] - m2[o] * inv2v;
  }
  for (int i = t; i < NC * (2 * NC2); i += nth) {
    int c = i / (2 * NC2), o4 = i % (2 * NC2);
    float val;
    if (o4 < NC2) val = Wg[o4 * NC2 + c] - Wg[o4 * NC2 + NC + c];
    else          val = Wg[(o4 - NC2) * NC2 + NC + c];
    Wuv[i] = val;
  }
  for (int i = t; i < NC2 * NC; i += nth) {
    int c = i / NC, o = i % NC;
    float inv = g2[o] / sqrtf(v2[o] + BN_EPS);
    W2f[i] = W2[o * NC2 + c] * inv;
  }
}

// ---------------- K2: feat = BN(W1 x + b1); fnT[n][0:96]=fn row, [96]=sum fn^2 ---------
__global__ __launch_bounds__(256) void k_feat(const float* __restrict__ x,
                                              const float* __restrict__ W1f,
                                              const float* __restrict__ b1f,
                                              float* __restrict__ feat,
                                              float* __restrict__ fnT) {
  __shared__ float w_lds[NC * NC];
  int b = blockIdx.y;
  int n = blockIdx.x * 256 + threadIdx.x;
  for (int i = threadIdx.x * 4; i < NC * NC; i += 1024)
    *(float4*)&w_lds[i] = *(const float4*)&W1f[i];
  __syncthreads();
  if (n < NPT) {
    const float* xb = x + (size_t)b * NC * NPT;
    float acc[NC];
#pragma unroll
    for (int o = 0; o < NC; ++o) acc[o] = b1f[o];
    for (int c = 0; c < NC; ++c) {
      float xv = xb[c * NPT + n];
#pragma unroll
      for (int o4 = 0; o4 < NC / 4; ++o4) {
        float4 wv = *(float4*)&w_lds[c * NC + o4 * 4];
        acc[o4 * 4 + 0] = fmaf(wv.x, xv, acc[o4 * 4 + 0]);
        acc[o4 * 4 + 1] = fmaf(wv.y, xv, acc[o4 * 4 + 1]);
        acc[o4 * 4 + 2] = fmaf(wv.z, xv, acc[o4 * 4 + 2]);
        acc[o4 * 4 + 3] = fmaf(wv.w, xv, acc[o4 * 4 + 3]);
      }
    }
    float sq = 0.f;
#pragma unroll
    for (int o = 0; o < NC; ++o) sq += acc[o] * acc[o];
    float den = fmaxf(sqrtf(sq), 1e-12f);
    float sqn = 0.f;
    float* fb = feat + (size_t)b * NC * NPT + n;
    float* fr = fnT + ((size_t)b * NPT + n) * RST;
#pragma unroll
    for (int o4 = 0; o4 < 24; ++o4) {
      float4 vv;
      float v0 = acc[o4 * 4 + 0] / den;
      float v1v = acc[o4 * 4 + 1] / den;
      float v2v = acc[o4 * 4 + 2] / den;
      float v3 = acc[o4 * 4 + 3] / den;
      vv.x = v0; vv.y = v1v; vv.z = v2v; vv.w = v3;
      sqn += v0 * v0 + v1v * v1v + v2v * v2v + v3 * v3;
      *(float4*)&fr[o4 * 4] = vv;
      fb[(size_t)(o4 * 4 + 0) * NPT] = acc[o4 * 4 + 0];
      fb[(size_t)(o4 * 4 + 1) * NPT] = acc[o4 * 4 + 1];
      fb[(size_t)(o4 * 4 + 2) * NPT] = acc[o4 * 4 + 2];
      fb[(size_t)(o4 * 4 + 3) * NPT] = acc[o4 * 4 + 3];
    }
    fr[96] = sqn;
  }
}

// ---------------- K3: exact KNN, lane-per-row, broadcast LDS columns -------------------
// Block = 256 thr = 256 rows (4 waves). Each block owns (batch, jsplit, rowblock):
// scans 112 j-columns staged in LDS; lane holds its row in 96 VGPRs; score = dot-0.5*sq_j
// (descending == ascending ref-dist); top-9 as sorted u64 (flipbits||j) in registers.
__global__ __launch_bounds__(256, 3) void k_knn(const float* __restrict__ fnT,
                                                u64* __restrict__ pk) {
  int bid = blockIdx.x;
  int b = bid & 7;            // XCD affinity: per-batch fnT stays in one XCD's L2
  int t = bid >> 3;           // 0..363
  int jsplit = t % JSPLIT;
  int rb4 = t / JSPLIT;       // 0..12
  int j0 = jsplit * JTASK;
  int n = rb4 * 256 + (int)threadIdx.x;   // 0..3327; >=NPT lanes duplicate row, no store
  int nc = n < NPT ? n : NPT - 1;

  __shared__ float4 tile[JTASK * RST / 4];   // 2912 float4 = 46592 B

  const float* rowp = fnT + ((size_t)b * NPT + nc) * RST;
  float r[96];
#pragma unroll
  for (int c4 = 0; c4 < 24; ++c4) {
    float4 v = *(const float4*)&rowp[c4 * 4];
    r[c4 * 4 + 0] = v.x; r[c4 * 4 + 1] = v.y;
    r[c4 * 4 + 2] = v.z; r[c4 * 4 + 3] = v.w;
  }

  const float4* src = (const float4*)(fnT + ((size_t)b * NPT + j0) * RST);
  for (int i = threadIdx.x; i < JTASK * RST / 4; i += 256)
    tile[i] = src[i];
  __syncthreads();

  u64 k9[NK];
#pragma unroll
  for (int k = 0; k < NK; ++k) k9[k] = ~0ull;

  const float* tp = (const float*)tile;
  for (int jj = 0; jj < JTASK; ++jj) {
    const float* cp = tp + jj * RST;     // wave-uniform address -> LDS broadcast
    float a0 = 0.f, a1 = 0.f, a2 = 0.f, a3 = 0.f;
#pragma unroll
    for (int c4 = 0; c4 < 24; ++c4) {
      float4 cv = *(const float4*)&cp[c4 * 4];
      a0 = fmaf(r[c4 * 4 + 0], cv.x, a0);
      a1 = fmaf(r[c4 * 4 + 1], cv.y, a1);
      a2 = fmaf(r[c4 * 4 + 2], cv.z, a2);
      a3 = fmaf(r[c4 * 4 + 3], cv.w, a3);
    }
    float score = fmaf(-0.5f, cp[96], (a0 + a1) + (a2 + a3));
    unsigned u = __float_as_uint(score);
    u ^= 0x80000000u | (unsigned)((int)u >> 31);  // monotone increasing map
    u = ~u;                                       // descending score = ascending dist
    u64 key = ((u64)u << 32) | (unsigned)(j0 + jj);
    if (key < k9[8]) {
      k9[8] = key;
#pragma unroll
      for (int s = 8; s > 0; --s) {
        u64 xx = k9[s - 1], yy = k9[s];
        bool sw = yy < xx;
        k9[s - 1] = sw ? yy : xx;
        k9[s]     = sw ? xx : yy;
      }
    }
  }

  if (n < NPT) {
    u64* op = pk + ((size_t)(b * NPT + n) * JSPLIT + jsplit) * NK;
#pragma unroll
    for (int k = 0; k < NK; ++k) op[k] = k9[k];
  }
}

// ---------------- K3b: merge the 28 sorted 9-lists per row ----------------------------
__global__ __launch_bounds__(256) void k_nnmerge(const u64* __restrict__ pk,
                                                 int* __restrict__ nn_idx) {
  int rg = blockIdx.x * 256 + threadIdx.x;
  if (rg >= NB * NPT) return;
  const u64* p = pk + (size_t)rg * JSPLIT * NK;
  u64 k9[NK];
#pragma unroll
  for (int k = 0; k < NK; ++k) k9[k] = p[k];   // list 0 already sorted
  for (int s = 1; s < JSPLIT; ++s) {
    const u64* ps = p + s * NK;
#pragma unroll
    for (int k = 0; k < NK; ++k) {
      u64 key = ps[k];
      if (key >= k9[8]) break;   // sorted source: rest can't qualify
      k9[8] = key;
#pragma unroll
      for (int q = 8; q > 0; --q) {
        u64 xx = k9[q - 1], yy = k9[q];
        bool sw = yy < xx;
        k9[q - 1] = sw ? yy : xx;
        k9[q]     = sw ? xx : yy;
      }
    }
  }
  int* op = nn_idx + (size_t)rg * NK;
#pragma unroll
  for (int k = 0; k < NK; ++k) op[k] = (int)(unsigned)(k9[k] & 0xFFFFFFFFu);
}

// ---------------- K4: uvt[b][n][0:192]=A@feat+bg, [192:384]=Bm@feat (transposed store) --
__global__ __launch_bounds__(256) void k_uv(const float* __restrict__ feat,
                                            const float* __restrict__ Wuv,
                                            const float* __restrict__ bg,
                                            float* __restrict__ uvt) {
  __shared__ float w_lds[24 * 384];
  int b = blockIdx.y;
  int n0 = blockIdx.x * 64;
  int lane = threadIdx.x & 63, og = threadIdx.x >> 6;
  int n = n0 + lane;
  const float* fb = feat + (size_t)b * NC * NPT;
  float acc[96];
#pragma unroll
  for (int oo = 0; oo < 96; ++oo) acc[oo] = 0.f;
  for (int ch = 0; ch < 4; ++ch) {
    __syncthreads();
    for (int i = threadIdx.x * 4; i < 24 * 384; i += 1024)
      *(float4*)&w_lds[i] = *(const float4*)&Wuv[ch * 24 * 384 + i];
    __syncthreads();
    for (int cc = 0; cc < 24; ++cc) {
      int c = ch * 24 + cc;
      float xv = fb[(size_t)c * NPT + n];
#pragma unroll
      for (int o4 = 0; o4 < 24; ++o4) {
        float4 wv = *(float4*)&w_lds[cc * 384 + og * 96 + o4 * 4];
        acc[o4 * 4 + 0] = fmaf(wv.x, xv, acc[o4 * 4 + 0]);
        acc[o4 * 4 + 1] = fmaf(wv.y, xv, acc[o4 * 4 + 1]);
        acc[o4 * 4 + 2] = fmaf(wv.z, xv, acc[o4 * 4 + 2]);
        acc[o4 * 4 + 3] = fmaf(wv.w, xv, acc[o4 * 4 + 3]);
      }
    }
  }
  float* up = uvt + ((size_t)b * NPT + n) * 384 + og * 96;
#pragma unroll
  for (int o4 = 0; o4 < 24; ++o4) {
    float4 v;
    v.x = acc[o4 * 4 + 0]; v.y = acc[o4 * 4 + 1];
    v.z = acc[o4 * 4 + 2]; v.w = acc[o4 * 4 + 3];
    if (og < 2) {
      int ob = og * 96 + o4 * 4;
      v.x += bg[ob + 0]; v.y += bg[ob + 1]; v.z += bg[ob + 2]; v.w += bg[ob + 3];
    }
    *(float4*)&up[o4 * 4] = v;
  }
}

// ---------------- K5: agg_t[n][o] = relu(max_k (u[n][o] + v[idx[n][k]][o])) ------------
__global__ __launch_bounds__(192) void k_gather(const float* __restrict__ uvt,
                                                const int* __restrict__ nn_idx,
                                                float* __restrict__ aggt) {
  int fid = blockIdx.x;
  int b = fid & 7;      // XCD affinity for the per-batch v table
  int n = fid >> 3;
  int o = threadIdx.x;
  const float* base = uvt + (size_t)b * NPT * 384;
  const int* ip = nn_idx + ((size_t)b * NPT + n) * NK;
  float u = base[(size_t)n * 384 + o];
  float acc = -1e30f;
#pragma unroll
  for (int k = 0; k < NK; ++k) {
    int j = ip[k];
    float v = base[(size_t)j * 384 + 192 + o];
    acc = fmaxf(acc, u + v);
  }
  aggt[((size_t)b * NPT + n) * 192 + o] = fmaxf(acc, 0.f);
}

// ---------------- K6: out = W2f @ agg + b2f + residual ---------------------------------
__global__ __launch_bounds__(256) void k_out(const float* __restrict__ aggt,
                                             const float* __restrict__ W2f,
                                             const float* __restrict__ b2f,
                                             const float* __restrict__ x,
                                             float* __restrict__ out) {
  __shared__ float w_lds[96 * 96];
  __shared__ float a_lds[64 * 97];
  int b = blockIdx.y;
  int n0 = blockIdx.x * 64;
  int lane = threadIdx.x & 63, og = threadIdx.x >> 6;
  int n = n0 + lane;
  float acc[24];
#pragma unroll
  for (int oo = 0; oo < 24; ++oo) acc[oo] = 0.f;
  const float* ab = aggt + ((size_t)b * NPT + n0) * 192;
  for (int ch = 0; ch < 2; ++ch) {
    __syncthreads();
    for (int i = threadIdx.x * 4; i < 96 * 96; i += 1024)
      *(float4*)&w_lds[i] = *(const float4*)&W2f[ch * 96 * 96 + i];
    for (int fidx = threadIdx.x; fidx < 64 * 24; fidx += 256) {
      int rr = fidx / 24, cc4 = fidx % 24;
      float4 v = *(const float4*)&ab[(size_t)rr * 192 + ch * 96 + cc4 * 4];
      a_lds[rr * 97 + cc4 * 4 + 0] = v.x;
      a_lds[rr * 97 + cc4 * 4 + 1] = v.y;
      a_lds[rr * 97 + cc4 * 4 + 2] = v.z;
      a_lds[rr * 97 + cc4 * 4 + 3] = v.w;
    }
    __syncthreads();
    for (int cc = 0; cc < 96; ++cc) {
      float a = a_lds[lane * 97 + cc];
#pragma unroll
      for (int o4 = 0; o4 < 6; ++o4) {
        float4 wv = *(float4*)&w_lds[cc * 96 + og * 24 + o4 * 4];
        acc[o4 * 4 + 0] = fmaf(wv.x, a, acc[o4 * 4 + 0]);
        acc[o4 * 4 + 1] = fmaf(wv.y, a, acc[o4 * 4 + 1]);
        acc[o4 * 4 + 2] = fmaf(wv.z, a, acc[o4 * 4 + 2]);
        acc[o4 * 4 + 3] = fmaf(wv.w, a, acc[o4 * 4 + 3]);
      }
    }
  }
  const float* xb = x + (size_t)b * NC * NPT;
  float* ob = out + (size_t)b * NC * NPT;
#pragma unroll
  for (int oo = 0; oo < 24; ++oo) {
    int o = og * 24 + oo;
    ob[(size_t)o * NPT + n] = acc[oo] + b2f[o] + xb[(size_t)o * NPT + n];
  }
}

extern "C" void kernel_launch(void* const* d_in, const int* in_sizes, int n_in,
                              void* d_out, int out_size, void* d_ws, size_t ws_size,
                              hipStream_t stream) {
  const float* x  = (const float*)d_in[0];
  const float* W1 = (const float*)d_in[1];
  const float* b1 = (const float*)d_in[2];
  const float* g1 = (const float*)d_in[3];
  const float* be1= (const float*)d_in[4];
  const float* m1 = (const float*)d_in[5];
  const float* v1 = (const float*)d_in[6];
  const float* Wg = (const float*)d_in[7];
  const float* bg = (const float*)d_in[8];
  const float* W2 = (const float*)d_in[9];
  const float* b2 = (const float*)d_in[10];
  const float* g2 = (const float*)d_in[11];
  const float* be2= (const float*)d_in[12];
  const float* m2 = (const float*)d_in[13];
  const float* v2 = (const float*)d_in[14];
  float* out = (float*)d_out;

  float* ws = (float*)d_ws;
  size_t off = 0;
  float* feat = ws + off; off += (size_t)NB * NC * NPT;      // 2,408,448
  float* fnT  = ws + off; off += (size_t)NB * NPT * RST;     // 2,609,088
  float* uvt  = ws + off; off += (size_t)NB * NPT * 384;     // 9,633,792
  float* aggt = ws + off; off += (size_t)NB * NPT * 192;     // 4,816,896
  float* W1f  = ws + off; off += NC * NC;
  float* Wuv  = ws + off; off += NC * 2 * NC2;
  float* W2f  = ws + off; off += NC2 * NC;
  float* b1f  = ws + off; off += 128;
  float* b2f  = ws + off; off += 128;

  // Overlays (phase-disjoint): pk lives in uvt+aggt during knn (consumed by merge
  // before k_uv writes uvt); nn_idx lives in fnT (dead after k_knn).
  u64* pk = (u64*)uvt;            // 25088*28*9*8B = 50.6 MB <= uvt+aggt (57.8 MB)
  int* nn_idx = (int*)fnT;        // 0.9 MB <= fnT (10.4 MB)

  k_fuse<<<dim3(64), 256, 0, stream>>>(W1, b1, g1, be1, m1, v1, Wg, W2, b2, g2, be2, m2, v2,
                                       W1f, b1f, Wuv, W2f, b2f);
  k_feat<<<dim3(13, NB), 256, 0, stream>>>(x, W1f, b1f, feat, fnT);
  k_knn<<<dim3(NB * JSPLIT * 13), 256, 0, stream>>>(fnT, pk);
  k_nnmerge<<<dim3((NB * NPT + 255) / 256), 256, 0, stream>>>(pk, nn_idx);
  k_uv<<<dim3(NPT / 64, NB), 256, 0, stream>>>(feat, Wuv, bg, uvt);
  k_gather<<<dim3(NB * NPT), 192, 0, stream>>>(uvt, nn_idx, aggt);
  k_out<<<dim3(NPT / 64, NB), 256, 0, stream>>>(aggt, W2f, b2f, x, out);
}

// Round 5
// 746.367 us; speedup vs baseline: 1.0429x; 1.0429x over previous
//
#include <hip/hip_runtime.h>
#include <cstdint>

#define NB 8
#define NC 96
#define NC2 192
#define NPT 3136    // 56*56
#define NK 9
#define NL 8        // lists per row: 4 j-splits x 2 lane-halves
#define NCAND 16    // per-lane list depth == pooled candidate count
#define RST 104     // fnT row stride (96 fn + sq at [96] + pad)
static constexpr float BN_EPS = 1e-5f;
typedef unsigned long long u64;
typedef float f32x16 __attribute__((ext_vector_type(16)));
typedef short short8 __attribute__((ext_vector_type(8)));

__device__ inline unsigned short f32_to_bf16_rne(float x) {
  unsigned u = __float_as_uint(x);
  unsigned r = (u + 0x7FFFu + ((u >> 16) & 1u)) >> 16;
  return (unsigned short)r;
}

__device__ inline unsigned score_to_key_hi(float s) {
  unsigned u = __float_as_uint(s);
  u ^= 0x80000000u | (unsigned)((int)u >> 31);  // monotone increasing map
  return ~u;                                    // descending score = ascending dist
}

// ---------------- K1: fold BN into weights, build fused weight layouts ----------------
__global__ void k_fuse(const float* __restrict__ W1, const float* __restrict__ b1,
                       const float* __restrict__ g1, const float* __restrict__ be1,
                       const float* __restrict__ m1, const float* __restrict__ v1,
                       const float* __restrict__ Wg,
                       const float* __restrict__ W2, const float* __restrict__ b2,
                       const float* __restrict__ g2, const float* __restrict__ be2,
                       const float* __restrict__ m2, const float* __restrict__ v2,
                       float* __restrict__ W1f, float* __restrict__ b1f,
                       float* __restrict__ Wuv,
                       float* __restrict__ W2f, float* __restrict__ b2f) {
  int t = blockIdx.x * blockDim.x + threadIdx.x;
  int nth = gridDim.x * blockDim.x;
  for (int i = t; i < NC * NC; i += nth) {
    int c = i / NC, o = i % NC;
    float inv = g1[o] / sqrtf(v1[o] + BN_EPS);
    W1f[i] = W1[o * NC + c] * inv;
  }
  for (int o = t; o < NC; o += nth) {
    float inv = g1[o] / sqrtf(v1[o] + BN_EPS);
    b1f[o] = b1[o] * inv + be1[o] - m1[o] * inv;
    float inv2v = g2[o] / sqrtf(v2[o] + BN_EPS);
    b2f[o] = b2[o] * inv2v + be2[o] - m2[o] * inv2v;
  }
  for (int i = t; i < NC * (2 * NC2); i += nth) {
    int c = i / (2 * NC2), o4 = i % (2 * NC2);
    float val;
    if (o4 < NC2) val = Wg[o4 * NC2 + c] - Wg[o4 * NC2 + NC + c];
    else          val = Wg[(o4 - NC2) * NC2 + NC + c];
    Wuv[i] = val;
  }
  for (int i = t; i < NC2 * NC; i += nth) {
    int c = i / NC, o = i % NC;
    float inv = g2[o] / sqrtf(v2[o] + BN_EPS);
    W2f[i] = W2[o * NC2 + c] * inv;
  }
}

// ------- K2: feat = BN(W1 x + b1); fnT = f32 fn rows (+sq); hiT/loT = bf16 split -------
__global__ __launch_bounds__(256) void k_feat(const float* __restrict__ x,
                                              const float* __restrict__ W1f,
                                              const float* __restrict__ b1f,
                                              float* __restrict__ feat,
                                              float* __restrict__ fnT,
                                              unsigned short* __restrict__ hiT,
                                              unsigned short* __restrict__ loT) {
  __shared__ float w_lds[NC * NC];
  int b = blockIdx.y;
  int n = blockIdx.x * 256 + threadIdx.x;
  for (int i = threadIdx.x * 4; i < NC * NC; i += 1024)
    *(float4*)&w_lds[i] = *(const float4*)&W1f[i];
  __syncthreads();
  if (n < NPT) {
    const float* xb = x + (size_t)b * NC * NPT;
    float acc[NC];
#pragma unroll
    for (int o = 0; o < NC; ++o) acc[o] = b1f[o];
    for (int c = 0; c < NC; ++c) {
      float xv = xb[c * NPT + n];
#pragma unroll
      for (int o4 = 0; o4 < NC / 4; ++o4) {
        float4 wv = *(float4*)&w_lds[c * NC + o4 * 4];
        acc[o4 * 4 + 0] = fmaf(wv.x, xv, acc[o4 * 4 + 0]);
        acc[o4 * 4 + 1] = fmaf(wv.y, xv, acc[o4 * 4 + 1]);
        acc[o4 * 4 + 2] = fmaf(wv.z, xv, acc[o4 * 4 + 2]);
        acc[o4 * 4 + 3] = fmaf(wv.w, xv, acc[o4 * 4 + 3]);
      }
    }
    float sq = 0.f;
#pragma unroll
    for (int o = 0; o < NC; ++o) sq += acc[o] * acc[o];
    float den = fmaxf(sqrtf(sq), 1e-12f);
    float sqn = 0.f;
    float* fb = feat + (size_t)b * NC * NPT + n;
    float* fr = fnT + ((size_t)b * NPT + n) * RST;
    unsigned short* hr = hiT + ((size_t)b * NPT + n) * NC;
    unsigned short* lr = loT + ((size_t)b * NPT + n) * NC;
#pragma unroll
    for (int o4 = 0; o4 < 24; ++o4) {
      u64 hp = 0, lp = 0;
      float4 vv;
#pragma unroll
      for (int e = 0; e < 4; ++e) {
        float f = acc[o4 * 4 + e];
        fb[(size_t)(o4 * 4 + e) * NPT] = f;
        float v = f / den;
        ((float*)&vv)[e] = v;
        sqn += v * v;
        unsigned short h = f32_to_bf16_rne(v);
        float hv = __uint_as_float(((unsigned)h) << 16);
        unsigned short l = f32_to_bf16_rne(v - hv);
        hp |= ((u64)h) << (16 * e);
        lp |= ((u64)l) << (16 * e);
      }
      *(float4*)&fr[o4 * 4] = vv;
      *(u64*)&hr[o4 * 4] = hp;
      *(u64*)&lr[o4 * 4] = lp;
    }
    fr[96] = sqn;
  }
}

// ---------------- K3: KNN candidate gen via compensated bf16 MFMA ----------------------
// Block = 256 thr = 4 waves on one (b, iblock32); wave w scans j-quarter w.
// Lane owns output col i = iblk*32 + (lane&31); keeps top-16 u64 keys (~dotbits || j).
// dot = hi.hi + hi.lo + lo.hi  (3 passes of mfma_f32_32x32x16_bf16, f32 accum).
__global__ __launch_bounds__(256, 3) void k_knn(const unsigned short* __restrict__ hiT,
                                                const unsigned short* __restrict__ loT,
                                                u64* __restrict__ pk) {
  int bid = blockIdx.x;
  int b = bid & 7;            // XCD affinity: per-batch rows stay in one XCD's L2
  int iblk = bid >> 3;        // 0..97
  int wq = threadIdx.x >> 6;  // j-quarter
  int lane = threadIdx.x & 63;
  int col = lane & 31;
  int half = lane >> 5;       // k-group (also j-row-half selector in C layout)
  int i = iblk * 32 + col;

  const unsigned short* hb = hiT + (size_t)b * NPT * NC;
  const unsigned short* lb = loT + (size_t)b * NPT * NC;

  short8 Bh[6], Bl[6];
  {
    const unsigned short* ih = hb + (size_t)i * NC + half * 8;
    const unsigned short* il = lb + (size_t)i * NC + half * 8;
#pragma unroll
    for (int ch = 0; ch < 6; ++ch) {
      Bh[ch] = *(const short8*)(ih + ch * 16);
      Bl[ch] = *(const short8*)(il + ch * 16);
    }
  }

  u64 k16[NCAND];
#pragma unroll
  for (int k = 0; k < NCAND; ++k) k16[k] = ~0ull;

  int t0 = (98 * wq) / 4, t1 = (98 * (wq + 1)) / 4;
  for (int t = t0; t < t1; ++t) {
    int j0 = t * 32;
    const unsigned short* ah = hb + (size_t)(j0 + col) * NC + half * 8;
    const unsigned short* al = lb + (size_t)(j0 + col) * NC + half * 8;
    f32x16 acc0, acc1;
#pragma unroll
    for (int r = 0; r < 16; ++r) { acc0[r] = 0.f; acc1[r] = 0.f; }
    {
      short8 A[6];
#pragma unroll
      for (int ch = 0; ch < 6; ++ch) A[ch] = *(const short8*)(ah + ch * 16);
#pragma unroll
      for (int ch = 0; ch < 6; ++ch)
        acc0 = __builtin_amdgcn_mfma_f32_32x32x16_bf16(A[ch], Bh[ch], acc0, 0, 0, 0);
#pragma unroll
      for (int ch = 0; ch < 6; ++ch)
        acc1 = __builtin_amdgcn_mfma_f32_32x32x16_bf16(A[ch], Bl[ch], acc1, 0, 0, 0);
    }
    {
      short8 A[6];
#pragma unroll
      for (int ch = 0; ch < 6; ++ch) A[ch] = *(const short8*)(al + ch * 16);
#pragma unroll
      for (int ch = 0; ch < 6; ++ch)
        acc0 = __builtin_amdgcn_mfma_f32_32x32x16_bf16(A[ch], Bh[ch], acc0, 0, 0, 0);
    }
#pragma unroll
    for (int r = 0; r < 16; ++r) {
      float s = acc0[r] + acc1[r];
      int jl = (r & 3) + 8 * (r >> 2) + 4 * half;
      u64 key = ((u64)score_to_key_hi(s) << 32) | (unsigned)(j0 + jl);
      if (key < k16[NCAND - 1]) {
        k16[NCAND - 1] = key;
#pragma unroll
        for (int s8 = NCAND - 1; s8 > 0; --s8) {
          u64 xx = k16[s8 - 1], yy = k16[s8];
          bool sw = yy < xx;
          k16[s8 - 1] = sw ? yy : xx;
          k16[s8]     = sw ? xx : yy;
        }
      }
    }
  }

  u64* op = pk + ((size_t)((size_t)b * NPT + i) * NL + (wq * 2 + half)) * NCAND;
#pragma unroll
  for (int k = 0; k < NCAND; ++k) op[k] = k16[k];
}

// ---------------- K3b: merge NL sorted 16-lists per row -> top-16 candidate set --------
__global__ __launch_bounds__(256) void k_nnmerge(const u64* __restrict__ pk,
                                                 int* __restrict__ cand) {
  int rg = blockIdx.x * 256 + threadIdx.x;
  if (rg >= NB * NPT) return;
  const u64* p = pk + (size_t)rg * NL * NCAND;
  u64 kk[NCAND];
#pragma unroll
  for (int k = 0; k < NCAND; ++k) kk[k] = p[k];   // list 0 already sorted
  for (int s = 1; s < NL; ++s) {
    const u64* ps = p + s * NCAND;
#pragma unroll
    for (int k = 0; k < NCAND; ++k) {
      u64 key = ps[k];
      if (key >= kk[NCAND - 1]) break;   // sorted source: rest can't qualify
      kk[NCAND - 1] = key;
#pragma unroll
      for (int q = NCAND - 1; q > 0; --q) {
        u64 xx = kk[q - 1], yy = kk[q];
        bool sw = yy < xx;
        kk[q - 1] = sw ? yy : xx;
        kk[q]     = sw ? xx : yy;
      }
    }
  }
  int* op = cand + (size_t)rg * NCAND;
#pragma unroll
  for (int k = 0; k < NCAND; ++k) op[k] = (int)(unsigned)(kk[k] & 0xFFFFFFFFu);
}

// ---------------- K3c: f32 rescore of 16 candidates -> exact top-9 ---------------------
// Wave per row. 16 cands x 4 lanes; each lane does 24 channels; shfl-reduce; lane 0 sorts.
__global__ __launch_bounds__(256) void k_rescore(const float* __restrict__ fnT,
                                                 const int* __restrict__ cand,
                                                 int* __restrict__ nn_idx) {
  __shared__ u64 kl[4][NCAND];
  int wid = threadIdx.x >> 6, lane = threadIdx.x & 63;
  int row = blockIdx.x * 4 + wid;            // 0..25087 (grid exact)
  int b = row / NPT;
  int c = lane >> 2, sub = lane & 3;
  int j = cand[(size_t)row * NCAND + c];
  const float* fi = fnT + (size_t)row * RST + sub * 24;
  const float* fj = fnT + (size_t)(b * NPT + j) * RST + sub * 24;
  float p = 0.f;
#pragma unroll
  for (int c4 = 0; c4 < 6; ++c4) {
    float4 a = *(const float4*)&fi[c4 * 4];
    float4 v = *(const float4*)&fj[c4 * 4];
    p = fmaf(a.x, v.x, p); p = fmaf(a.y, v.y, p);
    p = fmaf(a.z, v.z, p); p = fmaf(a.w, v.w, p);
  }
  p += __shfl_xor(p, 1);
  p += __shfl_xor(p, 2);
  if (sub == 0) {
    float sqj = fnT[(size_t)(b * NPT + j) * RST + 96];
    float score = fmaf(-0.5f, sqj, p);
    kl[wid][c] = ((u64)score_to_key_hi(score) << 32) | (unsigned)j;
  }
  __syncthreads();
  if (lane == 0) {
    u64 k9[NK];
#pragma unroll
    for (int k = 0; k < NK; ++k) k9[k] = ~0ull;
#pragma unroll
    for (int t = 0; t < NCAND; ++t) {
      u64 key = kl[wid][t];
      if (key < k9[NK - 1]) {
        k9[NK - 1] = key;
#pragma unroll
        for (int q = NK - 1; q > 0; --q) {
          u64 xx = k9[q - 1], yy = k9[q];
          bool sw = yy < xx;
          k9[q - 1] = sw ? yy : xx;
          k9[q]     = sw ? xx : yy;
        }
      }
    }
    int* op = nn_idx + (size_t)row * NK;
#pragma unroll
    for (int k = 0; k < NK; ++k) op[k] = (int)(unsigned)(k9[k] & 0xFFFFFFFFu);
  }
}

// ---------------- K4: uvt[b][n][0:192]=A@feat+bg, [192:384]=Bm@feat (transposed store) --
__global__ __launch_bounds__(256) void k_uv(const float* __restrict__ feat,
                                            const float* __restrict__ Wuv,
                                            const float* __restrict__ bg,
                                            float* __restrict__ uvt) {
  __shared__ float w_lds[24 * 384];
  int b = blockIdx.y;
  int n0 = blockIdx.x * 64;
  int lane = threadIdx.x & 63, og = threadIdx.x >> 6;
  int n = n0 + lane;
  const float* fb = feat + (size_t)b * NC * NPT;
  float acc[96];
#pragma unroll
  for (int oo = 0; oo < 96; ++oo) acc[oo] = 0.f;
  for (int ch = 0; ch < 4; ++ch) {
    __syncthreads();
    for (int i = threadIdx.x * 4; i < 24 * 384; i += 1024)
      *(float4*)&w_lds[i] = *(const float4*)&Wuv[ch * 24 * 384 + i];
    __syncthreads();
    for (int cc = 0; cc < 24; ++cc) {
      int c = ch * 24 + cc;
      float xv = fb[(size_t)c * NPT + n];
#pragma unroll
      for (int o4 = 0; o4 < 24; ++o4) {
        float4 wv = *(float4*)&w_lds[cc * 384 + og * 96 + o4 * 4];
        acc[o4 * 4 + 0] = fmaf(wv.x, xv, acc[o4 * 4 + 0]);
        acc[o4 * 4 + 1] = fmaf(wv.y, xv, acc[o4 * 4 + 1]);
        acc[o4 * 4 + 2] = fmaf(wv.z, xv, acc[o4 * 4 + 2]);
        acc[o4 * 4 + 3] = fmaf(wv.w, xv, acc[o4 * 4 + 3]);
      }
    }
  }
  float* up = uvt + ((size_t)b * NPT + n) * 384 + og * 96;
#pragma unroll
  for (int o4 = 0; o4 < 24; ++o4) {
    float4 v;
    v.x = acc[o4 * 4 + 0]; v.y = acc[o4 * 4 + 1];
    v.z = acc[o4 * 4 + 2]; v.w = acc[o4 * 4 + 3];
    if (og < 2) {
      int ob = og * 96 + o4 * 4;
      v.x += bg[ob + 0]; v.y += bg[ob + 1]; v.z += bg[ob + 2]; v.w += bg[ob + 3];
    }
    *(float4*)&up[o4 * 4] = v;
  }
}

// ---------------- K5: agg_t[n][o] = relu(max_k (u[n][o] + v[idx[n][k]][o])) ------------
__global__ __launch_bounds__(192) void k_gather(const float* __restrict__ uvt,
                                                const int* __restrict__ nn_idx,
                                                float* __restrict__ aggt) {
  int fid = blockIdx.x;
  int b = fid & 7;      // XCD affinity for the per-batch v table
  int n = fid >> 3;
  int o = threadIdx.x;
  const float* base = uvt + (size_t)b * NPT * 384;
  const int* ip = nn_idx + ((size_t)b * NPT + n) * NK;
  float u = base[(size_t)n * 384 + o];
  float acc = -1e30f;
#pragma unroll
  for (int k = 0; k < NK; ++k) {
    int j = ip[k];
    float v = base[(size_t)j * 384 + 192 + o];
    acc = fmaxf(acc, u + v);
  }
  aggt[((size_t)b * NPT + n) * 192 + o] = fmaxf(acc, 0.f);
}

// ---------------- K6: out = W2f @ agg + b2f + residual ---------------------------------
__global__ __launch_bounds__(256) void k_out(const float* __restrict__ aggt,
                                             const float* __restrict__ W2f,
                                             const float* __restrict__ b2f,
                                             const float* __restrict__ x,
                                             float* __restrict__ out) {
  __shared__ float w_lds[96 * 96];
  __shared__ float a_lds[64 * 97];
  int b = blockIdx.y;
  int n0 = blockIdx.x * 64;
  int lane = threadIdx.x & 63, og = threadIdx.x >> 6;
  int n = n0 + lane;
  float acc[24];
#pragma unroll
  for (int oo = 0; oo < 24; ++oo) acc[oo] = 0.f;
  const float* ab = aggt + ((size_t)b * NPT + n0) * 192;
  for (int ch = 0; ch < 2; ++ch) {
    __syncthreads();
    for (int i = threadIdx.x * 4; i < 96 * 96; i += 1024)
      *(float4*)&w_lds[i] = *(const float4*)&W2f[ch * 96 * 96 + i];
    for (int fidx = threadIdx.x; fidx < 64 * 24; fidx += 256) {
      int rr = fidx / 24, cc4 = fidx % 24;
      float4 v = *(const float4*)&ab[(size_t)rr * 192 + ch * 96 + cc4 * 4];
      a_lds[rr * 97 + cc4 * 4 + 0] = v.x;
      a_lds[rr * 97 + cc4 * 4 + 1] = v.y;
      a_lds[rr * 97 + cc4 * 4 + 2] = v.z;
      a_lds[rr * 97 + cc4 * 4 + 3] = v.w;
    }
    __syncthreads();
    for (int cc = 0; cc < 96; ++cc) {
      float a = a_lds[lane * 97 + cc];
#pragma unroll
      for (int o4 = 0; o4 < 6; ++o4) {
        float4 wv = *(float4*)&w_lds[cc * 96 + og * 24 + o4 * 4];
        acc[o4 * 4 + 0] = fmaf(wv.x, a, acc[o4 * 4 + 0]);
        acc[o4 * 4 + 1] = fmaf(wv.y, a, acc[o4 * 4 + 1]);
        acc[o4 * 4 + 2] = fmaf(wv.z, a, acc[o4 * 4 + 2]);
        acc[o4 * 4 + 3] = fmaf(wv.w, a, acc[o4 * 4 + 3]);
      }
    }
  }
  const float* xb = x + (size_t)b * NC * NPT;
  float* ob = out + (size_t)b * NC * NPT;
#pragma unroll
  for (int oo = 0; oo < 24; ++oo) {
    int o = og * 24 + oo;
    ob[(size_t)o * NPT + n] = acc[oo] + b2f[o] + xb[(size_t)o * NPT + n];
  }
}

extern "C" void kernel_launch(void* const* d_in, const int* in_sizes, int n_in,
                              void* d_out, int out_size, void* d_ws, size_t ws_size,
                              hipStream_t stream) {
  const float* x  = (const float*)d_in[0];
  const float* W1 = (const float*)d_in[1];
  const float* b1 = (const float*)d_in[2];
  const float* g1 = (const float*)d_in[3];
  const float* be1= (const float*)d_in[4];
  const float* m1 = (const float*)d_in[5];
  const float* v1 = (const float*)d_in[6];
  const float* Wg = (const float*)d_in[7];
  const float* bg = (const float*)d_in[8];
  const float* W2 = (const float*)d_in[9];
  const float* b2 = (const float*)d_in[10];
  const float* g2 = (const float*)d_in[11];
  const float* be2= (const float*)d_in[12];
  const float* m2 = (const float*)d_in[13];
  const float* v2 = (const float*)d_in[14];
  float* out = (float*)d_out;

  float* ws = (float*)d_ws;
  size_t off = 0;
  float* feat = ws + off; off += (size_t)NB * NC * NPT;             // 9.6 MB
  unsigned short* hiT = (unsigned short*)(ws + off); off += (size_t)NB * NPT * NC / 2;
  unsigned short* loT = (unsigned short*)(ws + off); off += (size_t)NB * NPT * NC / 2;
  float* uvt  = ws + off; off += (size_t)NB * NPT * 384;            // 38.5 MB
  float* aggt = ws + off; off += (size_t)NB * NPT * 192;            // 19.3 MB
  float* W1f  = ws + off; off += NC * NC;
  float* Wuv  = ws + off; off += NC * 2 * NC2;
  float* W2f  = ws + off; off += NC2 * NC;
  float* b1f  = ws + off; off += 128;
  float* b2f  = ws + off; off += 128;

  // Phase-disjoint overlays:
  //   fnT (10.4 MB) -> aggt (19.3 MB): fnT dead after k_rescore, aggt written by k_gather.
  //   pk  (25.7 MB) -> uvt  (38.5 MB): pk consumed by k_nnmerge before k_uv writes uvt.
  //   cand (1.6 MB) -> hiT region (4.8 MB): hiT dead after k_knn.
  //   nn_idx (0.9 MB) -> loT region (4.8 MB): loT dead after k_knn.
  float* fnT  = aggt;
  u64* pk     = (u64*)uvt;
  int* cand   = (int*)hiT;
  int* nn_idx = (int*)loT;

  k_fuse<<<dim3(64), 256, 0, stream>>>(W1, b1, g1, be1, m1, v1, Wg, W2, b2, g2, be2, m2, v2,
                                       W1f, b1f, Wuv, W2f, b2f);
  k_feat<<<dim3(13, NB), 256, 0, stream>>>(x, W1f, b1f, feat, fnT, hiT, loT);
  k_knn<<<dim3(NB * (NPT / 32)), 256, 0, stream>>>(hiT, loT, pk);
  k_nnmerge<<<dim3((NB * NPT + 255) / 256), 256, 0, stream>>>(pk, cand);
  k_rescore<<<dim3(NB * NPT / 4), 256, 0, stream>>>(fnT, cand, nn_idx);
  k_uv<<<dim3(NPT / 64, NB), 256, 0, stream>>>(feat, Wuv, bg, uvt);
  k_gather<<<dim3(NB * NPT), 192, 0, stream>>>(uvt, nn_idx, aggt);
  k_out<<<dim3(NPT / 64, NB), 256, 0, stream>>>(aggt, W2f, b2f, x, out);
}

// Round 6
// 457.880 us; speedup vs baseline: 1.7000x; 1.6300x over previous
//
#include <hip/hip_runtime.h>
#include <cstdint>

#define NB 8
#define NC 96
#define NC2 192
#define NPT 3136    // 56*56
#define NK 9
#define NL 8        // lists per row: 4 j-splits x 2 lane-halves
#define NDEP 10     // per-lane list depth
#define NCAND 16    // pooled candidate count per row
#define RST 104     // fnT row stride (96 fn + sq at [96] + pad)
static constexpr float BN_EPS = 1e-5f;
typedef unsigned long long u64;
typedef float f32x16 __attribute__((ext_vector_type(16)));
typedef short short8 __attribute__((ext_vector_type(8)));

__device__ inline unsigned short f32_to_bf16_rne(float x) {
  unsigned u = __float_as_uint(x);
  unsigned r = (u + 0x7FFFu + ((u >> 16) & 1u)) >> 16;
  return (unsigned short)r;
}

__device__ inline unsigned score_to_key(float s) {
  unsigned u = __float_as_uint(s);
  u ^= 0x80000000u | (unsigned)((int)u >> 31);  // monotone increasing map
  return ~u;                                    // descending score = ascending dist
}

// ---------------- K1: fold BN into weights, build fused weight layouts ----------------
__global__ void k_fuse(const float* __restrict__ W1, const float* __restrict__ b1,
                       const float* __restrict__ g1, const float* __restrict__ be1,
                       const float* __restrict__ m1, const float* __restrict__ v1,
                       const float* __restrict__ Wg,
                       const float* __restrict__ W2, const float* __restrict__ b2,
                       const float* __restrict__ g2, const float* __restrict__ be2,
                       const float* __restrict__ m2, const float* __restrict__ v2,
                       float* __restrict__ W1f, float* __restrict__ b1f,
                       float* __restrict__ Wuv,
                       float* __restrict__ W2f, float* __restrict__ b2f) {
  int t = blockIdx.x * blockDim.x + threadIdx.x;
  int nth = gridDim.x * blockDim.x;
  for (int i = t; i < NC * NC; i += nth) {
    int c = i / NC, o = i % NC;
    float inv = g1[o] / sqrtf(v1[o] + BN_EPS);
    W1f[i] = W1[o * NC + c] * inv;
  }
  for (int o = t; o < NC; o += nth) {
    float inv = g1[o] / sqrtf(v1[o] + BN_EPS);
    b1f[o] = b1[o] * inv + be1[o] - m1[o] * inv;
    float inv2v = g2[o] / sqrtf(v2[o] + BN_EPS);
    b2f[o] = b2[o] * inv2v + be2[o] - m2[o] * inv2v;
  }
  for (int i = t; i < NC * (2 * NC2); i += nth) {
    int c = i / (2 * NC2), o4 = i % (2 * NC2);
    float val;
    if (o4 < NC2) val = Wg[o4 * NC2 + c] - Wg[o4 * NC2 + NC + c];
    else          val = Wg[(o4 - NC2) * NC2 + NC + c];
    Wuv[i] = val;
  }
  for (int i = t; i < NC2 * NC; i += nth) {
    int c = i / NC, o = i % NC;
    float inv = g2[o] / sqrtf(v2[o] + BN_EPS);
    W2f[i] = W2[o * NC2 + c] * inv;
  }
}

// ------- K2: feat = BN(W1 x + b1); fnT = f32 fn rows (+sq); hiT/loT = bf16 split -------
__global__ __launch_bounds__(256) void k_feat(const float* __restrict__ x,
                                              const float* __restrict__ W1f,
                                              const float* __restrict__ b1f,
                                              float* __restrict__ feat,
                                              float* __restrict__ fnT,
                                              unsigned short* __restrict__ hiT,
                                              unsigned short* __restrict__ loT) {
  __shared__ float w_lds[NC * NC];
  int b = blockIdx.y;
  int n = blockIdx.x * 256 + threadIdx.x;
  for (int i = threadIdx.x * 4; i < NC * NC; i += 1024)
    *(float4*)&w_lds[i] = *(const float4*)&W1f[i];
  __syncthreads();
  if (n < NPT) {
    const float* xb = x + (size_t)b * NC * NPT;
    float acc[NC];
#pragma unroll
    for (int o = 0; o < NC; ++o) acc[o] = b1f[o];
    for (int c = 0; c < NC; ++c) {
      float xv = xb[c * NPT + n];
#pragma unroll
      for (int o4 = 0; o4 < NC / 4; ++o4) {
        float4 wv = *(float4*)&w_lds[c * NC + o4 * 4];
        acc[o4 * 4 + 0] = fmaf(wv.x, xv, acc[o4 * 4 + 0]);
        acc[o4 * 4 + 1] = fmaf(wv.y, xv, acc[o4 * 4 + 1]);
        acc[o4 * 4 + 2] = fmaf(wv.z, xv, acc[o4 * 4 + 2]);
        acc[o4 * 4 + 3] = fmaf(wv.w, xv, acc[o4 * 4 + 3]);
      }
    }
    float sq = 0.f;
#pragma unroll
    for (int o = 0; o < NC; ++o) sq += acc[o] * acc[o];
    float den = fmaxf(sqrtf(sq), 1e-12f);
    float sqn = 0.f;
    float* fb = feat + (size_t)b * NC * NPT + n;
    float* fr = fnT + ((size_t)b * NPT + n) * RST;
    unsigned short* hr = hiT + ((size_t)b * NPT + n) * NC;
    unsigned short* lr = loT + ((size_t)b * NPT + n) * NC;
#pragma unroll
    for (int o4 = 0; o4 < 24; ++o4) {
      u64 hp = 0, lp = 0;
      float4 vv;
#pragma unroll
      for (int e = 0; e < 4; ++e) {
        float f = acc[o4 * 4 + e];
        fb[(size_t)(o4 * 4 + e) * NPT] = f;
        float v = f / den;
        ((float*)&vv)[e] = v;
        sqn += v * v;
        unsigned short h = f32_to_bf16_rne(v);
        float hv = __uint_as_float(((unsigned)h) << 16);
        unsigned short l = f32_to_bf16_rne(v - hv);
        hp |= ((u64)h) << (16 * e);
        lp |= ((u64)l) << (16 * e);
      }
      *(float4*)&fr[o4 * 4] = vv;
      *(u64*)&hr[o4 * 4] = hp;
      *(u64*)&lr[o4 * 4] = lp;
    }
    fr[96] = sqn;
  }
}

// ---------------- K3: KNN candidate gen via compensated bf16 MFMA ----------------------
// Block = 256 thr = 4 waves on one (b, iblock32); wave w scans j-quarter w.
// Lane owns col i = iblk*32 + (lane&31); keeps top-10 (u32 key, u32 id) pairs.
// dot = hi.hi + hi.lo + lo.hi chained into ONE f32 accumulator (order-free).
// Selection: unconditional replace-worst + 9-step bubble (no divergent branch,
// compile-time indices only -> stays in VGPRs).
__global__ __launch_bounds__(256, 3) void k_knn(const unsigned short* __restrict__ hiT,
                                                const unsigned short* __restrict__ loT,
                                                u64* __restrict__ pk) {
  int bid = blockIdx.x;
  int b = bid & 7;            // XCD affinity: per-batch rows stay in one XCD's L2
  int iblk = bid >> 3;        // 0..97
  int wq = threadIdx.x >> 6;  // j-quarter
  int lane = threadIdx.x & 63;
  int col = lane & 31;
  int half = lane >> 5;       // k-group (also j-row-half selector in C layout)
  int i = iblk * 32 + col;

  const unsigned short* hb = hiT + (size_t)b * NPT * NC;
  const unsigned short* lb = loT + (size_t)b * NPT * NC;

  short8 Bh[6], Bl[6];
  {
    const unsigned short* ih = hb + (size_t)i * NC + half * 8;
    const unsigned short* il = lb + (size_t)i * NC + half * 8;
#pragma unroll
    for (int ch = 0; ch < 6; ++ch) {
      Bh[ch] = *(const short8*)(ih + ch * 16);
      Bl[ch] = *(const short8*)(il + ch * 16);
    }
  }

  unsigned kk[NDEP], id[NDEP];
#pragma unroll
  for (int k = 0; k < NDEP; ++k) { kk[k] = 0xFFFFFFFFu; id[k] = 0u; }

  int t0 = (98 * wq) / 4, t1 = (98 * (wq + 1)) / 4;
  for (int t = t0; t < t1; ++t) {
    int j0 = t * 32;
    const unsigned short* ah = hb + (size_t)(j0 + col) * NC + half * 8;
    const unsigned short* al = lb + (size_t)(j0 + col) * NC + half * 8;
    f32x16 acc;
#pragma unroll
    for (int r = 0; r < 16; ++r) acc[r] = 0.f;
    {
      short8 A[6];
#pragma unroll
      for (int ch = 0; ch < 6; ++ch) A[ch] = *(const short8*)(ah + ch * 16);
#pragma unroll
      for (int ch = 0; ch < 6; ++ch)
        acc = __builtin_amdgcn_mfma_f32_32x32x16_bf16(A[ch], Bh[ch], acc, 0, 0, 0);
#pragma unroll
      for (int ch = 0; ch < 6; ++ch)
        acc = __builtin_amdgcn_mfma_f32_32x32x16_bf16(A[ch], Bl[ch], acc, 0, 0, 0);
    }
    {
      short8 A[6];
#pragma unroll
      for (int ch = 0; ch < 6; ++ch) A[ch] = *(const short8*)(al + ch * 16);
#pragma unroll
      for (int ch = 0; ch < 6; ++ch)
        acc = __builtin_amdgcn_mfma_f32_32x32x16_bf16(A[ch], Bh[ch], acc, 0, 0, 0);
    }
    int j0h = j0 + 4 * half;
#pragma unroll
    for (int r = 0; r < 16; ++r) {
      unsigned u = score_to_key(acc[r]);
      unsigned jd = (unsigned)(j0h + (r & 3) + 8 * (r >> 2));
      // replace-worst (unconditional select)
      bool c = u < kk[NDEP - 1];
      kk[NDEP - 1] = c ? u : kk[NDEP - 1];
      id[NDEP - 1] = c ? jd : id[NDEP - 1];
      // bubble toward front (unconditional, compile-time indices)
#pragma unroll
      for (int s = NDEP - 1; s > 0; --s) {
        bool sw = kk[s] < kk[s - 1];
        unsigned tk = kk[s - 1], ti = id[s - 1];
        kk[s - 1] = sw ? kk[s] : tk;
        id[s - 1] = sw ? id[s] : ti;
        kk[s] = sw ? tk : kk[s];
        id[s] = sw ? ti : id[s];
      }
    }
  }

  u64* op = pk + ((size_t)((size_t)b * NPT + i) * NL + (wq * 2 + half)) * NDEP;
#pragma unroll
  for (int k = 0; k < NDEP; ++k) op[k] = ((u64)kk[k] << 32) | id[k];
}

// ---------------- K3b: merge NL sorted 10-lists per row -> top-16 candidate set --------
__global__ __launch_bounds__(256) void k_nnmerge(const u64* __restrict__ pk,
                                                 int* __restrict__ cand) {
  int rg = blockIdx.x * 256 + threadIdx.x;
  if (rg >= NB * NPT) return;
  const u64* p = pk + (size_t)rg * NL * NDEP;
  u64 kc[NCAND];
#pragma unroll
  for (int k = 0; k < NCAND; ++k) kc[k] = ~0ull;
#pragma unroll
  for (int k = 0; k < NDEP; ++k) kc[k] = p[k];   // list 0 sorted; rest stay ~0
  for (int s = 1; s < NL; ++s) {
    const u64* ps = p + s * NDEP;
#pragma unroll
    for (int k = 0; k < NDEP; ++k) {
      u64 key = ps[k];
      if (key >= kc[NCAND - 1]) break;   // sorted source: rest can't qualify
      kc[NCAND - 1] = key;
#pragma unroll
      for (int q = NCAND - 1; q > 0; --q) {
        u64 xx = kc[q - 1], yy = kc[q];
        bool sw = yy < xx;
        kc[q - 1] = sw ? yy : xx;
        kc[q]     = sw ? xx : yy;
      }
    }
  }
  int* op = cand + (size_t)rg * NCAND;
#pragma unroll
  for (int k = 0; k < NCAND; ++k) op[k] = (int)(unsigned)(kc[k] & 0xFFFFFFFFu);
}

// ---------------- K3c: f32 rescore of 16 candidates -> exact top-9 ---------------------
// Wave per row. 16 cands x 4 lanes; each lane does 24 channels; shfl-reduce; lane 0 sorts.
__global__ __launch_bounds__(256) void k_rescore(const float* __restrict__ fnT,
                                                 const int* __restrict__ cand,
                                                 int* __restrict__ nn_idx) {
  __shared__ u64 kl[4][NCAND];
  int wid = threadIdx.x >> 6, lane = threadIdx.x & 63;
  int row = blockIdx.x * 4 + wid;            // 0..25087 (grid exact)
  int b = row / NPT;
  int c = lane >> 2, sub = lane & 3;
  int j = cand[(size_t)row * NCAND + c];
  const float* fi = fnT + (size_t)row * RST + sub * 24;
  const float* fj = fnT + (size_t)(b * NPT + j) * RST + sub * 24;
  float p = 0.f;
#pragma unroll
  for (int c4 = 0; c4 < 6; ++c4) {
    float4 a = *(const float4*)&fi[c4 * 4];
    float4 v = *(const float4*)&fj[c4 * 4];
    p = fmaf(a.x, v.x, p); p = fmaf(a.y, v.y, p);
    p = fmaf(a.z, v.z, p); p = fmaf(a.w, v.w, p);
  }
  p += __shfl_xor(p, 1);
  p += __shfl_xor(p, 2);
  if (sub == 0) {
    float sqj = fnT[(size_t)(b * NPT + j) * RST + 96];
    float score = fmaf(-0.5f, sqj, p);
    kl[wid][c] = ((u64)score_to_key(score) << 32) | (unsigned)j;
  }
  __syncthreads();
  if (lane == 0) {
    u64 k9[NK];
#pragma unroll
    for (int k = 0; k < NK; ++k) k9[k] = ~0ull;
#pragma unroll
    for (int t = 0; t < NCAND; ++t) {
      u64 key = kl[wid][t];
      if (key < k9[NK - 1]) {
        k9[NK - 1] = key;
#pragma unroll
        for (int q = NK - 1; q > 0; --q) {
          u64 xx = k9[q - 1], yy = k9[q];
          bool sw = yy < xx;
          k9[q - 1] = sw ? yy : xx;
          k9[q]     = sw ? xx : yy;
        }
      }
    }
    int* op = nn_idx + (size_t)row * NK;
#pragma unroll
    for (int k = 0; k < NK; ++k) op[k] = (int)(unsigned)(k9[k] & 0xFFFFFFFFu);
  }
}

// ---------------- K4: uvt[b][n][0:192]=A@feat+bg, [192:384]=Bm@feat (transposed store) --
__global__ __launch_bounds__(256) void k_uv(const float* __restrict__ feat,
                                            const float* __restrict__ Wuv,
                                            const float* __restrict__ bg,
                                            float* __restrict__ uvt) {
  __shared__ float w_lds[24 * 384];
  int b = blockIdx.y;
  int n0 = blockIdx.x * 64;
  int lane = threadIdx.x & 63, og = threadIdx.x >> 6;
  int n = n0 + lane;
  const float* fb = feat + (size_t)b * NC * NPT;
  float acc[96];
#pragma unroll
  for (int oo = 0; oo < 96; ++oo) acc[oo] = 0.f;
  for (int ch = 0; ch < 4; ++ch) {
    __syncthreads();
    for (int i = threadIdx.x * 4; i < 24 * 384; i += 1024)
      *(float4*)&w_lds[i] = *(const float4*)&Wuv[ch * 24 * 384 + i];
    __syncthreads();
    for (int cc = 0; cc < 24; ++cc) {
      int c = ch * 24 + cc;
      float xv = fb[(size_t)c * NPT + n];
#pragma unroll
      for (int o4 = 0; o4 < 24; ++o4) {
        float4 wv = *(float4*)&w_lds[cc * 384 + og * 96 + o4 * 4];
        acc[o4 * 4 + 0] = fmaf(wv.x, xv, acc[o4 * 4 + 0]);
        acc[o4 * 4 + 1] = fmaf(wv.y, xv, acc[o4 * 4 + 1]);
        acc[o4 * 4 + 2] = fmaf(wv.z, xv, acc[o4 * 4 + 2]);
        acc[o4 * 4 + 3] = fmaf(wv.w, xv, acc[o4 * 4 + 3]);
      }
    }
  }
  float* up = uvt + ((size_t)b * NPT + n) * 384 + og * 96;
#pragma unroll
  for (int o4 = 0; o4 < 24; ++o4) {
    float4 v;
    v.x = acc[o4 * 4 + 0]; v.y = acc[o4 * 4 + 1];
    v.z = acc[o4 * 4 + 2]; v.w = acc[o4 * 4 + 3];
    if (og < 2) {
      int ob = og * 96 + o4 * 4;
      v.x += bg[ob + 0]; v.y += bg[ob + 1]; v.z += bg[ob + 2]; v.w += bg[ob + 3];
    }
    *(float4*)&up[o4 * 4] = v;
  }
}

// ---------------- K5: agg_t[n][o] = relu(max_k (u[n][o] + v[idx[n][k]][o])) ------------
__global__ __launch_bounds__(192) void k_gather(const float* __restrict__ uvt,
                                                const int* __restrict__ nn_idx,
                                                float* __restrict__ aggt) {
  int fid = blockIdx.x;
  int b = fid & 7;      // XCD affinity for the per-batch v table
  int n = fid >> 3;
  int o = threadIdx.x;
  const float* base = uvt + (size_t)b * NPT * 384;
  const int* ip = nn_idx + ((size_t)b * NPT + n) * NK;
  float u = base[(size_t)n * 384 + o];
  float acc = -1e30f;
#pragma unroll
  for (int k = 0; k < NK; ++k) {
    int j = ip[k];
    float v = base[(size_t)j * 384 + 192 + o];
    acc = fmaxf(acc, u + v);
  }
  aggt[((size_t)b * NPT + n) * 192 + o] = fmaxf(acc, 0.f);
}

// ---------------- K6: out = W2f @ agg + b2f + residual ---------------------------------
__global__ __launch_bounds__(256) void k_out(const float* __restrict__ aggt,
                                             const float* __restrict__ W2f,
                                             const float* __restrict__ b2f,
                                             const float* __restrict__ x,
                                             float* __restrict__ out) {
  __shared__ float w_lds[96 * 96];
  __shared__ float a_lds[64 * 97];
  int b = blockIdx.y;
  int n0 = blockIdx.x * 64;
  int lane = threadIdx.x & 63, og = threadIdx.x >> 6;
  int n = n0 + lane;
  float acc[24];
#pragma unroll
  for (int oo = 0; oo < 24; ++oo) acc[oo] = 0.f;
  const float* ab = aggt + ((size_t)b * NPT + n0) * 192;
  for (int ch = 0; ch < 2; ++ch) {
    __syncthreads();
    for (int i = threadIdx.x * 4; i < 96 * 96; i += 1024)
      *(float4*)&w_lds[i] = *(const float4*)&W2f[ch * 96 * 96 + i];
    for (int fidx = threadIdx.x; fidx < 64 * 24; fidx += 256) {
      int rr = fidx / 24, cc4 = fidx % 24;
      float4 v = *(const float4*)&ab[(size_t)rr * 192 + ch * 96 + cc4 * 4];
      a_lds[rr * 97 + cc4 * 4 + 0] = v.x;
      a_lds[rr * 97 + cc4 * 4 + 1] = v.y;
      a_lds[rr * 97 + cc4 * 4 + 2] = v.z;
      a_lds[rr * 97 + cc4 * 4 + 3] = v.w;
    }
    __syncthreads();
    for (int cc = 0; cc < 96; ++cc) {
      float a = a_lds[lane * 97 + cc];
#pragma unroll
      for (int o4 = 0; o4 < 6; ++o4) {
        float4 wv = *(float4*)&w_lds[cc * 96 + og * 24 + o4 * 4];
        acc[o4 * 4 + 0] = fmaf(wv.x, a, acc[o4 * 4 + 0]);
        acc[o4 * 4 + 1] = fmaf(wv.y, a, acc[o4 * 4 + 1]);
        acc[o4 * 4 + 2] = fmaf(wv.z, a, acc[o4 * 4 + 2]);
        acc[o4 * 4 + 3] = fmaf(wv.w, a, acc[o4 * 4 + 3]);
      }
    }
  }
  const float* xb = x + (size_t)b * NC * NPT;
  float* ob = out + (size_t)b * NC * NPT;
#pragma unroll
  for (int oo = 0; oo < 24; ++oo) {
    int o = og * 24 + oo;
    ob[(size_t)o * NPT + n] = acc[oo] + b2f[o] + xb[(size_t)o * NPT + n];
  }
}

extern "C" void kernel_launch(void* const* d_in, const int* in_sizes, int n_in,
                              void* d_out, int out_size, void* d_ws, size_t ws_size,
                              hipStream_t stream) {
  const float* x  = (const float*)d_in[0];
  const float* W1 = (const float*)d_in[1];
  const float* b1 = (const float*)d_in[2];
  const float* g1 = (const float*)d_in[3];
  const float* be1= (const float*)d_in[4];
  const float* m1 = (const float*)d_in[5];
  const float* v1 = (const float*)d_in[6];
  const float* Wg = (const float*)d_in[7];
  const float* bg = (const float*)d_in[8];
  const float* W2 = (const float*)d_in[9];
  const float* b2 = (const float*)d_in[10];
  const float* g2 = (const float*)d_in[11];
  const float* be2= (const float*)d_in[12];
  const float* m2 = (const float*)d_in[13];
  const float* v2 = (const float*)d_in[14];
  float* out = (float*)d_out;

  float* ws = (float*)d_ws;
  size_t off = 0;
  float* feat = ws + off; off += (size_t)NB * NC * NPT;             // 9.6 MB
  unsigned short* hiT = (unsigned short*)(ws + off); off += (size_t)NB * NPT * NC / 2;
  unsigned short* loT = (unsigned short*)(ws + off); off += (size_t)NB * NPT * NC / 2;
  float* uvt  = ws + off; off += (size_t)NB * NPT * 384;            // 38.5 MB
  float* aggt = ws + off; off += (size_t)NB * NPT * 192;            // 19.3 MB
  float* W1f  = ws + off; off += NC * NC;
  float* Wuv  = ws + off; off += NC * 2 * NC2;
  float* W2f  = ws + off; off += NC2 * NC;
  float* b1f  = ws + off; off += 128;
  float* b2f  = ws + off; off += 128;

  // Phase-disjoint overlays:
  //   fnT (10.4 MB) -> aggt (19.3 MB): fnT dead after k_rescore, aggt written by k_gather.
  //   pk  (16.1 MB) -> uvt  (38.5 MB): pk consumed by k_nnmerge before k_uv writes uvt.
  //   cand (1.6 MB) -> hiT region (4.8 MB): hiT dead after k_knn.
  //   nn_idx (0.9 MB) -> loT region (4.8 MB): loT dead after k_knn.
  float* fnT  = aggt;
  u64* pk     = (u64*)uvt;
  int* cand   = (int*)hiT;
  int* nn_idx = (int*)loT;

  k_fuse<<<dim3(64), 256, 0, stream>>>(W1, b1, g1, be1, m1, v1, Wg, W2, b2, g2, be2, m2, v2,
                                       W1f, b1f, Wuv, W2f, b2f);
  k_feat<<<dim3(13, NB), 256, 0, stream>>>(x, W1f, b1f, feat, fnT, hiT, loT);
  k_knn<<<dim3(NB * (NPT / 32)), 256, 0, stream>>>(hiT, loT, pk);
  k_nnmerge<<<dim3((NB * NPT + 255) / 256), 256, 0, stream>>>(pk, cand);
  k_rescore<<<dim3(NB * NPT / 4), 256, 0, stream>>>(fnT, cand, nn_idx);
  k_uv<<<dim3(NPT / 64, NB), 256, 0, stream>>>(feat, Wuv, bg, uvt);
  k_gather<<<dim3(NB * NPT), 192, 0, stream>>>(uvt, nn_idx, aggt);
  k_out<<<dim3(NPT / 64, NB), 256, 0, stream>>>(aggt, W2f, b2f, x, out);
}

// Round 7
// 371.033 us; speedup vs baseline: 2.0980x; 1.2341x over previous
//
#include <hip/hip_runtime.h>
#include <cstdint>

#define NB 8
#define NC 96
#define NC2 192
#define NPT 3136    // 56*56
#define NK 9
#define NSPL 8      // j-splits
#define NLIST 16    // lists per row: 8 j-splits x 2 lane-halves
#define NDEP 9      // per-lane list depth (>= NK for superset guarantee)
#define NCAND 16    // pooled candidate count per row
#define RST 104     // fnT row stride (96 fn + sq at [96] + pad)
static constexpr float BN_EPS = 1e-5f;
typedef unsigned long long u64;
typedef float f32x16 __attribute__((ext_vector_type(16)));
typedef short short8 __attribute__((ext_vector_type(8)));

__device__ inline unsigned short f32_to_bf16_rne(float x) {
  unsigned u = __float_as_uint(x);
  unsigned r = (u + 0x7FFFu + ((u >> 16) & 1u)) >> 16;
  return (unsigned short)r;
}

__device__ inline unsigned score_to_key_exact(float s) {
  unsigned u = __float_as_uint(s);
  u ^= 0x80000000u | (unsigned)((int)u >> 31);  // monotone increasing map
  return ~u;                                    // descending score = ascending dist
}

// ---------------- K1: fold BN into weights, build fused weight layouts ----------------
__global__ void k_fuse(const float* __restrict__ W1, const float* __restrict__ b1,
                       const float* __restrict__ g1, const float* __restrict__ be1,
                       const float* __restrict__ m1, const float* __restrict__ v1,
                       const float* __restrict__ Wg,
                       const float* __restrict__ W2, const float* __restrict__ b2,
                       const float* __restrict__ g2, const float* __restrict__ be2,
                       const float* __restrict__ m2, const float* __restrict__ v2,
                       float* __restrict__ W1f, float* __restrict__ b1f,
                       float* __restrict__ Wuv,
                       float* __restrict__ W2f, float* __restrict__ b2f) {
  int t = blockIdx.x * blockDim.x + threadIdx.x;
  int nth = gridDim.x * blockDim.x;
  for (int i = t; i < NC * NC; i += nth) {
    int c = i / NC, o = i % NC;
    float inv = g1[o] / sqrtf(v1[o] + BN_EPS);
    W1f[i] = W1[o * NC + c] * inv;
  }
  for (int o = t; o < NC; o += nth) {
    float inv = g1[o] / sqrtf(v1[o] + BN_EPS);
    b1f[o] = b1[o] * inv + be1[o] - m1[o] * inv;
    float inv2v = g2[o] / sqrtf(v2[o] + BN_EPS);
    b2f[o] = b2[o] * inv2v + be2[o] - m2[o] * inv2v;
  }
  for (int i = t; i < NC * (2 * NC2); i += nth) {
    int c = i / (2 * NC2), o4 = i % (2 * NC2);
    float val;
    if (o4 < NC2) val = Wg[o4 * NC2 + c] - Wg[o4 * NC2 + NC + c];
    else          val = Wg[(o4 - NC2) * NC2 + NC + c];
    Wuv[i] = val;
  }
  for (int i = t; i < NC2 * NC; i += nth) {
    int c = i / NC, o = i % NC;
    float inv = g2[o] / sqrtf(v2[o] + BN_EPS);
    W2f[i] = W2[o * NC2 + c] * inv;
  }
}

// ------- K2: feat = BN(W1 x + b1); fnT = f32 fn rows (+sq); hiT/loT = bf16 split -------
__global__ __launch_bounds__(128) void k_feat(const float* __restrict__ x,
                                              const float* __restrict__ W1f,
                                              const float* __restrict__ b1f,
                                              float* __restrict__ feat,
                                              float* __restrict__ fnT,
                                              unsigned short* __restrict__ hiT,
                                              unsigned short* __restrict__ loT) {
  __shared__ float w_lds[NC * NC];
  int b = blockIdx.y;
  int n = blockIdx.x * 128 + threadIdx.x;
  for (int i = threadIdx.x * 4; i < NC * NC; i += 512)
    *(float4*)&w_lds[i] = *(const float4*)&W1f[i];
  __syncthreads();
  if (n < NPT) {
    const float* xb = x + (size_t)b * NC * NPT;
    float acc[NC];
#pragma unroll
    for (int o = 0; o < NC; ++o) acc[o] = b1f[o];
    for (int c = 0; c < NC; ++c) {
      float xv = xb[c * NPT + n];
#pragma unroll
      for (int o4 = 0; o4 < NC / 4; ++o4) {
        float4 wv = *(float4*)&w_lds[c * NC + o4 * 4];
        acc[o4 * 4 + 0] = fmaf(wv.x, xv, acc[o4 * 4 + 0]);
        acc[o4 * 4 + 1] = fmaf(wv.y, xv, acc[o4 * 4 + 1]);
        acc[o4 * 4 + 2] = fmaf(wv.z, xv, acc[o4 * 4 + 2]);
        acc[o4 * 4 + 3] = fmaf(wv.w, xv, acc[o4 * 4 + 3]);
      }
    }
    float sq = 0.f;
#pragma unroll
    for (int o = 0; o < NC; ++o) sq += acc[o] * acc[o];
    float den = fmaxf(sqrtf(sq), 1e-12f);
    float sqn = 0.f;
    float* fb = feat + (size_t)b * NC * NPT + n;
    float* fr = fnT + ((size_t)b * NPT + n) * RST;
    unsigned short* hr = hiT + ((size_t)b * NPT + n) * NC;
    unsigned short* lr = loT + ((size_t)b * NPT + n) * NC;
#pragma unroll
    for (int o4 = 0; o4 < 24; ++o4) {
      u64 hp = 0, lp = 0;
      float4 vv;
#pragma unroll
      for (int e = 0; e < 4; ++e) {
        float f = acc[o4 * 4 + e];
        fb[(size_t)(o4 * 4 + e) * NPT] = f;
        float v = f / den;
        ((float*)&vv)[e] = v;
        sqn += v * v;
        unsigned short h = f32_to_bf16_rne(v);
        float hv = __uint_as_float(((unsigned)h) << 16);
        unsigned short l = f32_to_bf16_rne(v - hv);
        hp |= ((u64)h) << (16 * e);
        lp |= ((u64)l) << (16 * e);
      }
      *(float4*)&fr[o4 * 4] = vv;
      *(u64*)&hr[o4 * 4] = hp;
      *(u64*)&lr[o4 * 4] = lp;
    }
    fr[96] = sqn;
  }
}

// ---------------- K3: KNN candidate gen via compensated bf16 MFMA ----------------------
// Grid 1568 = 8 b x 98 iblk x 2 jpairs; 4 waves/block; wave handles jsplit = jp*4+wq.
// Lane owns col i = iblk*32 + (lane&31); keeps top-9 packed u32 keys:
//   key = (bits(score+2.0f) & 0xFFFFFE00) | rel_j   (23-bit score, 9-bit rel id)
// dot = hi.hi + hi.lo + lo.hi chained into ONE f32 accumulator (order-free).
// Selection: unconditional replace-worst + 8-step bubble, descending (kk[0] = best).
__global__ __launch_bounds__(256, 4) void k_knn(const unsigned short* __restrict__ hiT,
                                                const unsigned short* __restrict__ loT,
                                                unsigned* __restrict__ pk) {
  int bid = blockIdx.x;
  int b = bid & 7;            // XCD affinity: per-batch rows stay in one XCD's L2
  int r2 = bid >> 3;          // 0..195
  int iblk = r2 % 98;
  int jp = r2 / 98;           // 0..1
  int wq = threadIdx.x >> 6;  // 0..3
  int jsplit = jp * 4 + wq;   // 0..7
  int lane = threadIdx.x & 63;
  int col = lane & 31;
  int half = lane >> 5;
  int i = iblk * 32 + col;

  const unsigned short* hb = hiT + (size_t)b * NPT * NC;
  const unsigned short* lb = loT + (size_t)b * NPT * NC;

  short8 Bh[6], Bl[6];
  {
    const unsigned short* ih = hb + (size_t)i * NC + half * 8;
    const unsigned short* il = lb + (size_t)i * NC + half * 8;
#pragma unroll
    for (int ch = 0; ch < 6; ++ch) {
      Bh[ch] = *(const short8*)(ih + ch * 16);
      Bl[ch] = *(const short8*)(il + ch * 16);
    }
  }

  unsigned kk[NDEP];
#pragma unroll
  for (int k = 0; k < NDEP; ++k) kk[k] = 0u;   // 0 < any real key (bits of +1..3)

  int t0 = (98 * jsplit) >> 3, t1 = (98 * (jsplit + 1)) >> 3;
  int jbase = t0 * 32;
  for (int t = t0; t < t1; ++t) {
    int j0 = t * 32;
    const unsigned short* ah = hb + (size_t)(j0 + col) * NC + half * 8;
    const unsigned short* al = lb + (size_t)(j0 + col) * NC + half * 8;
    f32x16 acc;
#pragma unroll
    for (int r = 0; r < 16; ++r) acc[r] = 0.f;
    {
      short8 A[6];
#pragma unroll
      for (int ch = 0; ch < 6; ++ch) A[ch] = *(const short8*)(ah + ch * 16);
#pragma unroll
      for (int ch = 0; ch < 6; ++ch)
        acc = __builtin_amdgcn_mfma_f32_32x32x16_bf16(A[ch], Bh[ch], acc, 0, 0, 0);
#pragma unroll
      for (int ch = 0; ch < 6; ++ch)
        acc = __builtin_amdgcn_mfma_f32_32x32x16_bf16(A[ch], Bl[ch], acc, 0, 0, 0);
    }
    {
      short8 A[6];
#pragma unroll
      for (int ch = 0; ch < 6; ++ch) A[ch] = *(const short8*)(al + ch * 16);
#pragma unroll
      for (int ch = 0; ch < 6; ++ch)
        acc = __builtin_amdgcn_mfma_f32_32x32x16_bf16(A[ch], Bh[ch], acc, 0, 0, 0);
    }
    unsigned relbase = (unsigned)(j0 - jbase + 4 * half);
#pragma unroll
    for (int r = 0; r < 16; ++r) {
      unsigned kb = __float_as_uint(acc[r] + 2.0f);
      unsigned key = (kb & 0xFFFFFE00u) | (relbase + (unsigned)((r & 3) + 8 * (r >> 2)));
      // replace-worst (descending list: kk[0] best, kk[8] worst)
      bool c = key > kk[NDEP - 1];
      kk[NDEP - 1] = c ? key : kk[NDEP - 1];
#pragma unroll
      for (int s = NDEP - 1; s > 0; --s) {
        bool sw = kk[s] > kk[s - 1];
        unsigned tk = kk[s - 1];
        kk[s - 1] = sw ? kk[s] : tk;
        kk[s]     = sw ? tk : kk[s];
      }
    }
  }

  unsigned* op = pk + ((size_t)((size_t)b * NPT + i) * NLIST + (jsplit * 2 + half)) * NDEP;
#pragma unroll
  for (int k = 0; k < NDEP; ++k) op[k] = kk[k];
}

// ---------------- K3b: merge NLIST sorted 9-lists per row -> top-16 candidate set ------
// Pool entries as u64 = (key32 << 4) | list_s  (keeps full 23-bit score + decodable j).
__global__ __launch_bounds__(256) void k_nnmerge(const unsigned* __restrict__ pk,
                                                 int* __restrict__ cand) {
  int rg = blockIdx.x * 256 + threadIdx.x;
  if (rg >= NB * NPT) return;
  const unsigned* p = pk + (size_t)rg * NLIST * NDEP;
  u64 kc[NCAND];
#pragma unroll
  for (int k = 0; k < NCAND; ++k) kc[k] = 0ull;
  for (int s = 0; s < NLIST; ++s) {
    const unsigned* ps = p + s * NDEP;
#pragma unroll
    for (int k = 0; k < NDEP; ++k) {
      u64 e = ((u64)ps[k] << 4) | (unsigned)s;
      if (e <= kc[NCAND - 1]) break;   // sorted desc source: rest can't qualify
      kc[NCAND - 1] = e;
#pragma unroll
      for (int q = NCAND - 1; q > 0; --q) {
        u64 xx = kc[q - 1], yy = kc[q];
        bool sw = yy > xx;
        kc[q - 1] = sw ? yy : xx;
        kc[q]     = sw ? xx : yy;
      }
    }
  }
  int* op = cand + (size_t)rg * NCAND;
#pragma unroll
  for (int k = 0; k < NCAND; ++k) {
    u64 e = kc[k];
    int s = (int)(e & 0xF);
    int rel = (int)((e >> 4) & 0x1FF);
    int jb = (((98 * (s >> 1)) >> 3) << 5);
    op[k] = jb + rel;
  }
}

// ---------------- K3c: f32 rescore of 16 candidates -> exact top-9 ---------------------
// Wave per row. 16 cands x 4 lanes; each lane does 24 channels; shfl-reduce; lane 0 sorts
// with full-precision u64 (exact score desc, j asc) keys -> exact reference selection.
__global__ __launch_bounds__(256) void k_rescore(const float* __restrict__ fnT,
                                                 const int* __restrict__ cand,
                                                 int* __restrict__ nn_idx) {
  __shared__ u64 kl[4][NCAND];
  int wid = threadIdx.x >> 6, lane = threadIdx.x & 63;
  int row = blockIdx.x * 4 + wid;            // 0..25087 (grid exact)
  int b = row / NPT;
  int c = lane >> 2, sub = lane & 3;
  int j = cand[(size_t)row * NCAND + c];
  const float* fi = fnT + (size_t)row * RST + sub * 24;
  const float* fj = fnT + (size_t)(b * NPT + j) * RST + sub * 24;
  float p = 0.f;
#pragma unroll
  for (int c4 = 0; c4 < 6; ++c4) {
    float4 a = *(const float4*)&fi[c4 * 4];
    float4 v = *(const float4*)&fj[c4 * 4];
    p = fmaf(a.x, v.x, p); p = fmaf(a.y, v.y, p);
    p = fmaf(a.z, v.z, p); p = fmaf(a.w, v.w, p);
  }
  p += __shfl_xor(p, 1);
  p += __shfl_xor(p, 2);
  if (sub == 0) {
    float sqj = fnT[(size_t)(b * NPT + j) * RST + 96];
    float score = fmaf(-0.5f, sqj, p);
    kl[wid][c] = ((u64)score_to_key_exact(score) << 32) | (unsigned)j;
  }
  __syncthreads();
  if (lane == 0) {
    u64 k9[NK];
#pragma unroll
    for (int k = 0; k < NK; ++k) k9[k] = ~0ull;
#pragma unroll
    for (int t = 0; t < NCAND; ++t) {
      u64 key = kl[wid][t];
      if (key < k9[NK - 1]) {
        k9[NK - 1] = key;
#pragma unroll
        for (int q = NK - 1; q > 0; --q) {
          u64 xx = k9[q - 1], yy = k9[q];
          bool sw = yy < xx;
          k9[q - 1] = sw ? yy : xx;
          k9[q]     = sw ? xx : yy;
        }
      }
    }
    int* op = nn_idx + (size_t)row * NK;
#pragma unroll
    for (int k = 0; k < NK; ++k) op[k] = (int)(unsigned)(k9[k] & 0xFFFFFFFFu);
  }
}

// ---------------- K4: uvt[b][n][0:192]=A@feat+bg, [192:384]=Bm@feat (transposed store) --
__global__ __launch_bounds__(256) void k_uv(const float* __restrict__ feat,
                                            const float* __restrict__ Wuv,
                                            const float* __restrict__ bg,
                                            float* __restrict__ uvt) {
  __shared__ float w_lds[24 * 384];
  int b = blockIdx.y;
  int n0 = blockIdx.x * 64;
  int lane = threadIdx.x & 63, og = threadIdx.x >> 6;
  int n = n0 + lane;
  const float* fb = feat + (size_t)b * NC * NPT;
  float acc[96];
#pragma unroll
  for (int oo = 0; oo < 96; ++oo) acc[oo] = 0.f;
  for (int ch = 0; ch < 4; ++ch) {
    __syncthreads();
    for (int i = threadIdx.x * 4; i < 24 * 384; i += 1024)
      *(float4*)&w_lds[i] = *(const float4*)&Wuv[ch * 24 * 384 + i];
    __syncthreads();
    for (int cc = 0; cc < 24; ++cc) {
      int c = ch * 24 + cc;
      float xv = fb[(size_t)c * NPT + n];
#pragma unroll
      for (int o4 = 0; o4 < 24; ++o4) {
        float4 wv = *(float4*)&w_lds[cc * 384 + og * 96 + o4 * 4];
        acc[o4 * 4 + 0] = fmaf(wv.x, xv, acc[o4 * 4 + 0]);
        acc[o4 * 4 + 1] = fmaf(wv.y, xv, acc[o4 * 4 + 1]);
        acc[o4 * 4 + 2] = fmaf(wv.z, xv, acc[o4 * 4 + 2]);
        acc[o4 * 4 + 3] = fmaf(wv.w, xv, acc[o4 * 4 + 3]);
      }
    }
  }
  float* up = uvt + ((size_t)b * NPT + n) * 384 + og * 96;
#pragma unroll
  for (int o4 = 0; o4 < 24; ++o4) {
    float4 v;
    v.x = acc[o4 * 4 + 0]; v.y = acc[o4 * 4 + 1];
    v.z = acc[o4 * 4 + 2]; v.w = acc[o4 * 4 + 3];
    if (og < 2) {
      int ob = og * 96 + o4 * 4;
      v.x += bg[ob + 0]; v.y += bg[ob + 1]; v.z += bg[ob + 2]; v.w += bg[ob + 3];
    }
    *(float4*)&up[o4 * 4] = v;
  }
}

// ---------------- K5: agg_t[n][o] = relu(max_k (u[n][o] + v[idx[n][k]][o])) ------------
// Wave per n, float4-wide: lanes 0..47 each own one float4 of the 192-wide row.
__global__ __launch_bounds__(256) void k_gather(const float* __restrict__ uvt,
                                                const int* __restrict__ nn_idx,
                                                float* __restrict__ aggt) {
  int bid = blockIdx.x;
  int b = bid & 7;      // XCD affinity for the per-batch v table
  int ng = bid >> 3;    // 0..783
  int wid = threadIdx.x >> 6, lane = threadIdx.x & 63;
  int n = ng * 4 + wid;
  if (lane >= 48) return;
  const float* base = uvt + (size_t)b * NPT * 384;
  const int* ip = nn_idx + ((size_t)b * NPT + n) * NK;
  float4 u = *(const float4*)&base[(size_t)n * 384 + lane * 4];
  float4 acc = make_float4(-1e30f, -1e30f, -1e30f, -1e30f);
#pragma unroll
  for (int k = 0; k < NK; ++k) {
    int j = ip[k];
    float4 v = *(const float4*)&base[(size_t)j * 384 + 192 + lane * 4];
    acc.x = fmaxf(acc.x, u.x + v.x);
    acc.y = fmaxf(acc.y, u.y + v.y);
    acc.z = fmaxf(acc.z, u.z + v.z);
    acc.w = fmaxf(acc.w, u.w + v.w);
  }
  float4 o;
  o.x = fmaxf(acc.x, 0.f); o.y = fmaxf(acc.y, 0.f);
  o.z = fmaxf(acc.z, 0.f); o.w = fmaxf(acc.w, 0.f);
  *(float4*)&aggt[((size_t)b * NPT + n) * 192 + lane * 4] = o;
}

// ---------------- K6: out = W2f @ agg + b2f + residual ---------------------------------
__global__ __launch_bounds__(256) void k_out(const float* __restrict__ aggt,
                                             const float* __restrict__ W2f,
                                             const float* __restrict__ b2f,
                                             const float* __restrict__ x,
                                             float* __restrict__ out) {
  __shared__ float w_lds[96 * 96];
  __shared__ float a_lds[64 * 97];
  int b = blockIdx.y;
  int n0 = blockIdx.x * 64;
  int lane = threadIdx.x & 63, og = threadIdx.x >> 6;
  int n = n0 + lane;
  float acc[24];
#pragma unroll
  for (int oo = 0; oo < 24; ++oo) acc[oo] = 0.f;
  const float* ab = aggt + ((size_t)b * NPT + n0) * 192;
  for (int ch = 0; ch < 2; ++ch) {
    __syncthreads();
    for (int i = threadIdx.x * 4; i < 96 * 96; i += 1024)
      *(float4*)&w_lds[i] = *(const float4*)&W2f[ch * 96 * 96 + i];
    for (int fidx = threadIdx.x; fidx < 64 * 24; fidx += 256) {
      int rr = fidx / 24, cc4 = fidx % 24;
      float4 v = *(const float4*)&ab[(size_t)rr * 192 + ch * 96 + cc4 * 4];
      a_lds[rr * 97 + cc4 * 4 + 0] = v.x;
      a_lds[rr * 97 + cc4 * 4 + 1] = v.y;
      a_lds[rr * 97 + cc4 * 4 + 2] = v.z;
      a_lds[rr * 97 + cc4 * 4 + 3] = v.w;
    }
    __syncthreads();
    for (int cc = 0; cc < 96; ++cc) {
      float a = a_lds[lane * 97 + cc];
#pragma unroll
      for (int o4 = 0; o4 < 6; ++o4) {
        float4 wv = *(float4*)&w_lds[cc * 96 + og * 24 + o4 * 4];
        acc[o4 * 4 + 0] = fmaf(wv.x, a, acc[o4 * 4 + 0]);
        acc[o4 * 4 + 1] = fmaf(wv.y, a, acc[o4 * 4 + 1]);
        acc[o4 * 4 + 2] = fmaf(wv.z, a, acc[o4 * 4 + 2]);
        acc[o4 * 4 + 3] = fmaf(wv.w, a, acc[o4 * 4 + 3]);
      }
    }
  }
  const float* xb = x + (size_t)b * NC * NPT;
  float* ob = out + (size_t)b * NC * NPT;
#pragma unroll
  for (int oo = 0; oo < 24; ++oo) {
    int o = og * 24 + oo;
    ob[(size_t)o * NPT + n] = acc[oo] + b2f[o] + xb[(size_t)o * NPT + n];
  }
}

extern "C" void kernel_launch(void* const* d_in, const int* in_sizes, int n_in,
                              void* d_out, int out_size, void* d_ws, size_t ws_size,
                              hipStream_t stream) {
  const float* x  = (const float*)d_in[0];
  const float* W1 = (const float*)d_in[1];
  const float* b1 = (const float*)d_in[2];
  const float* g1 = (const float*)d_in[3];
  const float* be1= (const float*)d_in[4];
  const float* m1 = (const float*)d_in[5];
  const float* v1 = (const float*)d_in[6];
  const float* Wg = (const float*)d_in[7];
  const float* bg = (const float*)d_in[8];
  const float* W2 = (const float*)d_in[9];
  const float* b2 = (const float*)d_in[10];
  const float* g2 = (const float*)d_in[11];
  const float* be2= (const float*)d_in[12];
  const float* m2 = (const float*)d_in[13];
  const float* v2 = (const float*)d_in[14];
  float* out = (float*)d_out;

  float* ws = (float*)d_ws;
  size_t off = 0;
  float* feat = ws + off; off += (size_t)NB * NC * NPT;             // 9.6 MB
  unsigned short* hiT = (unsigned short*)(ws + off); off += (size_t)NB * NPT * NC / 2;
  unsigned short* loT = (unsigned short*)(ws + off); off += (size_t)NB * NPT * NC / 2;
  float* uvt  = ws + off; off += (size_t)NB * NPT * 384;            // 38.5 MB
  float* aggt = ws + off; off += (size_t)NB * NPT * 192;            // 19.3 MB
  float* W1f  = ws + off; off += NC * NC;
  float* Wuv  = ws + off; off += NC * 2 * NC2;
  float* W2f  = ws + off; off += NC2 * NC;
  float* b1f  = ws + off; off += 128;
  float* b2f  = ws + off; off += 128;

  // Phase-disjoint overlays:
  //   fnT (10.4 MB) -> aggt (19.3 MB): fnT dead after k_rescore, aggt written by k_gather.
  //   pk  (14.4 MB) -> uvt  (38.5 MB): pk consumed by k_nnmerge before k_uv writes uvt.
  //   cand (1.6 MB) -> hiT region (4.8 MB): hiT dead after k_knn.
  //   nn_idx (0.9 MB) -> loT region (4.8 MB): loT dead after k_knn.
  float* fnT    = aggt;
  unsigned* pk  = (unsigned*)uvt;
  int* cand     = (int*)hiT;
  int* nn_idx   = (int*)loT;

  k_fuse<<<dim3(64), 256, 0, stream>>>(W1, b1, g1, be1, m1, v1, Wg, W2, b2, g2, be2, m2, v2,
                                       W1f, b1f, Wuv, W2f, b2f);
  k_feat<<<dim3(25, NB), 128, 0, stream>>>(x, W1f, b1f, feat, fnT, hiT, loT);
  k_knn<<<dim3(NB * 98 * 2), 256, 0, stream>>>(hiT, loT, pk);
  k_nnmerge<<<dim3((NB * NPT + 255) / 256), 256, 0, stream>>>(pk, cand);
  k_rescore<<<dim3(NB * NPT / 4), 256, 0, stream>>>(fnT, cand, nn_idx);
  k_uv<<<dim3(NPT / 64, NB), 256, 0, stream>>>(feat, Wuv, bg, uvt);
  k_gather<<<dim3(NB * NPT / 4), 256, 0, stream>>>(uvt, nn_idx, aggt);
  k_out<<<dim3(NPT / 64, NB), 256, 0, stream>>>(aggt, W2f, b2f, x, out);
}

// Round 8
// 314.475 us; speedup vs baseline: 2.4753x; 1.1798x over previous
//
#include <hip/hip_runtime.h>
#include <cstdint>

#define NB 8
#define NC 96
#define NC2 192
#define NPT 3136    // 56*56
#define NK 9
#define NSPL 8      // j-splits
#define NLIST 16    // lists per row: 8 j-splits x 2 lane-halves
#define NDEP 9      // per-lane list depth (>= NK for superset guarantee)
#define NCAND 16    // pooled candidate count per row
#define RST 104     // fnT row stride (96 fn + sq at [96] + pad)
#define UV_WSTR 292 // k_uv LDS per-ob stride: 12cc*24oo + 4 pad (mod32=4 -> 2-way, free)
#define OUT_WSTR 100// k_out LDS cc stride: 96 + 4 pad
static constexpr float BN_EPS = 1e-5f;
typedef unsigned long long u64;
typedef float f32x16 __attribute__((ext_vector_type(16)));
typedef short short8 __attribute__((ext_vector_type(8)));

__device__ inline unsigned short f32_to_bf16_rne(float x) {
  unsigned u = __float_as_uint(x);
  unsigned r = (u + 0x7FFFu + ((u >> 16) & 1u)) >> 16;
  return (unsigned short)r;
}

__device__ inline unsigned score_to_key_exact(float s) {
  unsigned u = __float_as_uint(s);
  u ^= 0x80000000u | (unsigned)((int)u >> 31);  // monotone increasing map
  return ~u;                                    // descending score = ascending dist
}

// ---------------- K1: fold BN into weights, build fused weight layouts ----------------
__global__ void k_fuse(const float* __restrict__ W1, const float* __restrict__ b1,
                       const float* __restrict__ g1, const float* __restrict__ be1,
                       const float* __restrict__ m1, const float* __restrict__ v1,
                       const float* __restrict__ Wg,
                       const float* __restrict__ W2, const float* __restrict__ b2,
                       const float* __restrict__ g2, const float* __restrict__ be2,
                       const float* __restrict__ m2, const float* __restrict__ v2,
                       float* __restrict__ W1f, float* __restrict__ b1f,
                       float* __restrict__ Wuv,
                       float* __restrict__ W2f, float* __restrict__ b2f) {
  int t = blockIdx.x * blockDim.x + threadIdx.x;
  int nth = gridDim.x * blockDim.x;
  for (int i = t; i < NC * NC; i += nth) {
    int c = i / NC, o = i % NC;
    float inv = g1[o] / sqrtf(v1[o] + BN_EPS);
    W1f[i] = W1[o * NC + c] * inv;
  }
  for (int o = t; o < NC; o += nth) {
    float inv = g1[o] / sqrtf(v1[o] + BN_EPS);
    b1f[o] = b1[o] * inv + be1[o] - m1[o] * inv;
    float inv2v = g2[o] / sqrtf(v2[o] + BN_EPS);
    b2f[o] = b2[o] * inv2v + be2[o] - m2[o] * inv2v;
  }
  for (int i = t; i < NC * (2 * NC2); i += nth) {
    int c = i / (2 * NC2), o4 = i % (2 * NC2);
    float val;
    if (o4 < NC2) val = Wg[o4 * NC2 + c] - Wg[o4 * NC2 + NC + c];
    else          val = Wg[(o4 - NC2) * NC2 + NC + c];
    Wuv[i] = val;
  }
  for (int i = t; i < NC2 * NC; i += nth) {
    int c = i / NC, o = i % NC;
    float inv = g2[o] / sqrtf(v2[o] + BN_EPS);
    W2f[i] = W2[o * NC2 + c] * inv;
  }
}

// ------- K2: feat = BN(W1 x + b1); fnT = f32 fn rows (+sq); hiT/loT = bf16 split -------
__global__ __launch_bounds__(128) void k_feat(const float* __restrict__ x,
                                              const float* __restrict__ W1f,
                                              const float* __restrict__ b1f,
                                              float* __restrict__ feat,
                                              float* __restrict__ fnT,
                                              unsigned short* __restrict__ hiT,
                                              unsigned short* __restrict__ loT) {
  __shared__ float w_lds[NC * NC];
  int b = blockIdx.y;
  int n = blockIdx.x * 128 + threadIdx.x;
  for (int i = threadIdx.x * 4; i < NC * NC; i += 512)
    *(float4*)&w_lds[i] = *(const float4*)&W1f[i];
  __syncthreads();
  if (n < NPT) {
    const float* xb = x + (size_t)b * NC * NPT;
    float acc[NC];
#pragma unroll
    for (int o = 0; o < NC; ++o) acc[o] = b1f[o];
    for (int c = 0; c < NC; ++c) {
      float xv = xb[c * NPT + n];
#pragma unroll
      for (int o4 = 0; o4 < NC / 4; ++o4) {
        float4 wv = *(float4*)&w_lds[c * NC + o4 * 4];
        acc[o4 * 4 + 0] = fmaf(wv.x, xv, acc[o4 * 4 + 0]);
        acc[o4 * 4 + 1] = fmaf(wv.y, xv, acc[o4 * 4 + 1]);
        acc[o4 * 4 + 2] = fmaf(wv.z, xv, acc[o4 * 4 + 2]);
        acc[o4 * 4 + 3] = fmaf(wv.w, xv, acc[o4 * 4 + 3]);
      }
    }
    float sq = 0.f;
#pragma unroll
    for (int o = 0; o < NC; ++o) sq += acc[o] * acc[o];
    float den = fmaxf(sqrtf(sq), 1e-12f);
    float sqn = 0.f;
    float* fb = feat + (size_t)b * NC * NPT + n;
    float* fr = fnT + ((size_t)b * NPT + n) * RST;
    unsigned short* hr = hiT + ((size_t)b * NPT + n) * NC;
    unsigned short* lr = loT + ((size_t)b * NPT + n) * NC;
#pragma unroll
    for (int o4 = 0; o4 < 24; ++o4) {
      u64 hp = 0, lp = 0;
      float4 vv;
#pragma unroll
      for (int e = 0; e < 4; ++e) {
        float f = acc[o4 * 4 + e];
        fb[(size_t)(o4 * 4 + e) * NPT] = f;
        float v = f / den;
        ((float*)&vv)[e] = v;
        sqn += v * v;
        unsigned short h = f32_to_bf16_rne(v);
        float hv = __uint_as_float(((unsigned)h) << 16);
        unsigned short l = f32_to_bf16_rne(v - hv);
        hp |= ((u64)h) << (16 * e);
        lp |= ((u64)l) << (16 * e);
      }
      *(float4*)&fr[o4 * 4] = vv;
      *(u64*)&hr[o4 * 4] = hp;
      *(u64*)&lr[o4 * 4] = lp;
    }
    fr[96] = sqn;
  }
}

// ---------------- K3: KNN candidate gen via compensated bf16 MFMA ----------------------
__global__ __launch_bounds__(256, 4) void k_knn(const unsigned short* __restrict__ hiT,
                                                const unsigned short* __restrict__ loT,
                                                unsigned* __restrict__ pk) {
  int bid = blockIdx.x;
  int b = bid & 7;            // XCD affinity: per-batch rows stay in one XCD's L2
  int r2 = bid >> 3;          // 0..195
  int iblk = r2 % 98;
  int jp = r2 / 98;           // 0..1
  int wq = threadIdx.x >> 6;  // 0..3
  int jsplit = jp * 4 + wq;   // 0..7
  int lane = threadIdx.x & 63;
  int col = lane & 31;
  int half = lane >> 5;
  int i = iblk * 32 + col;

  const unsigned short* hb = hiT + (size_t)b * NPT * NC;
  const unsigned short* lb = loT + (size_t)b * NPT * NC;

  short8 Bh[6], Bl[6];
  {
    const unsigned short* ih = hb + (size_t)i * NC + half * 8;
    const unsigned short* il = lb + (size_t)i * NC + half * 8;
#pragma unroll
    for (int ch = 0; ch < 6; ++ch) {
      Bh[ch] = *(const short8*)(ih + ch * 16);
      Bl[ch] = *(const short8*)(il + ch * 16);
    }
  }

  unsigned kk[NDEP];
#pragma unroll
  for (int k = 0; k < NDEP; ++k) kk[k] = 0u;   // 0 < any real key (bits of +1..3)

  int t0 = (98 * jsplit) >> 3, t1 = (98 * (jsplit + 1)) >> 3;
  int jbase = t0 * 32;
  for (int t = t0; t < t1; ++t) {
    int j0 = t * 32;
    const unsigned short* ah = hb + (size_t)(j0 + col) * NC + half * 8;
    const unsigned short* al = lb + (size_t)(j0 + col) * NC + half * 8;
    f32x16 acc;
#pragma unroll
    for (int r = 0; r < 16; ++r) acc[r] = 0.f;
    {
      short8 A[6];
#pragma unroll
      for (int ch = 0; ch < 6; ++ch) A[ch] = *(const short8*)(ah + ch * 16);
#pragma unroll
      for (int ch = 0; ch < 6; ++ch)
        acc = __builtin_amdgcn_mfma_f32_32x32x16_bf16(A[ch], Bh[ch], acc, 0, 0, 0);
#pragma unroll
      for (int ch = 0; ch < 6; ++ch)
        acc = __builtin_amdgcn_mfma_f32_32x32x16_bf16(A[ch], Bl[ch], acc, 0, 0, 0);
    }
    {
      short8 A[6];
#pragma unroll
      for (int ch = 0; ch < 6; ++ch) A[ch] = *(const short8*)(al + ch * 16);
#pragma unroll
      for (int ch = 0; ch < 6; ++ch)
        acc = __builtin_amdgcn_mfma_f32_32x32x16_bf16(A[ch], Bh[ch], acc, 0, 0, 0);
    }
    unsigned relbase = (unsigned)(j0 - jbase + 4 * half);
#pragma unroll
    for (int r = 0; r < 16; ++r) {
      unsigned kb = __float_as_uint(acc[r] + 2.0f);
      unsigned key = (kb & 0xFFFFFE00u) | (relbase + (unsigned)((r & 3) + 8 * (r >> 2)));
      bool c = key > kk[NDEP - 1];
      kk[NDEP - 1] = c ? key : kk[NDEP - 1];
#pragma unroll
      for (int s = NDEP - 1; s > 0; --s) {
        bool sw = kk[s] > kk[s - 1];
        unsigned tk = kk[s - 1];
        kk[s - 1] = sw ? kk[s] : tk;
        kk[s]     = sw ? tk : kk[s];
      }
    }
  }

  unsigned* op = pk + ((size_t)((size_t)b * NPT + i) * NLIST + (jsplit * 2 + half)) * NDEP;
#pragma unroll
  for (int k = 0; k < NDEP; ++k) op[k] = kk[k];
}

// ---------------- K3b: merge NLIST sorted 9-lists per row -> top-16 candidate set ------
__global__ __launch_bounds__(256) void k_nnmerge(const unsigned* __restrict__ pk,
                                                 int* __restrict__ cand) {
  int rg = blockIdx.x * 256 + threadIdx.x;
  if (rg >= NB * NPT) return;
  const unsigned* p = pk + (size_t)rg * NLIST * NDEP;
  u64 kc[NCAND];
#pragma unroll
  for (int k = 0; k < NCAND; ++k) kc[k] = 0ull;
  for (int s = 0; s < NLIST; ++s) {
    const unsigned* ps = p + s * NDEP;
#pragma unroll
    for (int k = 0; k < NDEP; ++k) {
      u64 e = ((u64)ps[k] << 4) | (unsigned)s;
      if (e <= kc[NCAND - 1]) break;   // sorted desc source: rest can't qualify
      kc[NCAND - 1] = e;
#pragma unroll
      for (int q = NCAND - 1; q > 0; --q) {
        u64 xx = kc[q - 1], yy = kc[q];
        bool sw = yy > xx;
        kc[q - 1] = sw ? yy : xx;
        kc[q]     = sw ? xx : yy;
      }
    }
  }
  int* op = cand + (size_t)rg * NCAND;
#pragma unroll
  for (int k = 0; k < NCAND; ++k) {
    u64 e = kc[k];
    int s = (int)(e & 0xF);
    int rel = (int)((e >> 4) & 0x1FF);
    int jb = (((98 * (s >> 1)) >> 3) << 5);
    op[k] = jb + rel;
  }
}

// ---------------- K3c: f32 rescore of 16 candidates -> exact top-9 ---------------------
__global__ __launch_bounds__(256) void k_rescore(const float* __restrict__ fnT,
                                                 const int* __restrict__ cand,
                                                 int* __restrict__ nn_idx) {
  __shared__ u64 kl[4][NCAND];
  int wid = threadIdx.x >> 6, lane = threadIdx.x & 63;
  int row = blockIdx.x * 4 + wid;            // 0..25087 (grid exact)
  int b = row / NPT;
  int c = lane >> 2, sub = lane & 3;
  int j = cand[(size_t)row * NCAND + c];
  const float* fi = fnT + (size_t)row * RST + sub * 24;
  const float* fj = fnT + (size_t)(b * NPT + j) * RST + sub * 24;
  float p = 0.f;
#pragma unroll
  for (int c4 = 0; c4 < 6; ++c4) {
    float4 a = *(const float4*)&fi[c4 * 4];
    float4 v = *(const float4*)&fj[c4 * 4];
    p = fmaf(a.x, v.x, p); p = fmaf(a.y, v.y, p);
    p = fmaf(a.z, v.z, p); p = fmaf(a.w, v.w, p);
  }
  p += __shfl_xor(p, 1);
  p += __shfl_xor(p, 2);
  if (sub == 0) {
    float sqj = fnT[(size_t)(b * NPT + j) * RST + 96];
    float score = fmaf(-0.5f, sqj, p);
    kl[wid][c] = ((u64)score_to_key_exact(score) << 32) | (unsigned)j;
  }
  __syncthreads();
  if (lane == 0) {
    u64 k9[NK];
#pragma unroll
    for (int k = 0; k < NK; ++k) k9[k] = ~0ull;
#pragma unroll
    for (int t = 0; t < NCAND; ++t) {
      u64 key = kl[wid][t];
      if (key < k9[NK - 1]) {
        k9[NK - 1] = key;
#pragma unroll
        for (int q = NK - 1; q > 0; --q) {
          u64 xx = k9[q - 1], yy = k9[q];
          bool sw = yy < xx;
          k9[q - 1] = sw ? yy : xx;
          k9[q]     = sw ? xx : yy;
        }
      }
    }
    int* op = nn_idx + (size_t)row * NK;
#pragma unroll
    for (int k = 0; k < NK; ++k) op[k] = (int)(unsigned)(k9[k] & 0xFFFFFFFFu);
  }
}

// ---------------- K4: uvt = [A;B] @ feat (+bg on u-half), transposed store -------------
// 1-wave blocks, 16 n each. lane = (nq = lane>>4, ob = lane&15); thread owns
// 4 n x 24 o. Per c: 1 b128 feat-broadcast + 6 b128 W -> 96 FMA (VALU-bound).
__global__ __launch_bounds__(64, 2) void k_uv(const float* __restrict__ feat,
                                              const float* __restrict__ Wuv,
                                              const float* __restrict__ bg,
                                              float* __restrict__ uvt) {
  int bid = blockIdx.x;      // 1568
  int b = bid & 7;           // XCD affinity for per-batch feat
  int ng = bid >> 3;         // 0..195
  int n0 = ng * 16;
  int lane = threadIdx.x;
  int ob = lane & 15, nq = lane >> 4;

  __shared__ float w_lds[16 * UV_WSTR];   // 18688 B
  __shared__ float f_lds[12 * 16];        // 768 B

  const float* fb = feat + (size_t)b * NC * NPT;
  float acc[4][24];
#pragma unroll
  for (int q = 0; q < 4; ++q)
#pragma unroll
    for (int oo = 0; oo < 24; ++oo) acc[q][oo] = 0.f;

  for (int ch = 0; ch < 8; ++ch) {
    __syncthreads();
    {  // stage W chunk (12 c x 384 o) into [ob][cc][24] padded
      const float* wsrc = Wuv + ch * 12 * 384;
#pragma unroll
      for (int it = 0; it < 18; ++it) {
        int i = lane * 4 + it * 256;
        float4 v = *(const float4*)&wsrc[i];
        int cc = i / 384, o = i % 384;
        *(float4*)&w_lds[(o / 24) * UV_WSTR + cc * 24 + (o % 24)] = v;
      }
      // stage feat chunk (12 c x 16 n)
#pragma unroll
      for (int it = 0; it < 3; ++it) {
        int i = lane + it * 64;
        int cc = i >> 4, nn = i & 15;
        f_lds[i] = fb[(size_t)(ch * 12 + cc) * NPT + n0 + nn];
      }
    }
    __syncthreads();
#pragma unroll
    for (int cc = 0; cc < 12; ++cc) {
      float4 a = *(const float4*)&f_lds[cc * 16 + nq * 4];
      const float* wp = &w_lds[ob * UV_WSTR + cc * 24];
#pragma unroll
      for (int o4 = 0; o4 < 6; ++o4) {
        float4 w = *(const float4*)&wp[o4 * 4];
#pragma unroll
        for (int e = 0; e < 4; ++e) {
          float we = ((const float*)&w)[e];
          acc[0][o4 * 4 + e] = fmaf(we, a.x, acc[0][o4 * 4 + e]);
          acc[1][o4 * 4 + e] = fmaf(we, a.y, acc[1][o4 * 4 + e]);
          acc[2][o4 * 4 + e] = fmaf(we, a.z, acc[2][o4 * 4 + e]);
          acc[3][o4 * 4 + e] = fmaf(we, a.w, acc[3][o4 * 4 + e]);
        }
      }
    }
  }

  float bias[24];
#pragma unroll
  for (int oo = 0; oo < 24; ++oo) bias[oo] = 0.f;
  if (ob < 8) {
#pragma unroll
    for (int o4 = 0; o4 < 6; ++o4) {
      float4 bv = *(const float4*)&bg[ob * 24 + o4 * 4];
      bias[o4 * 4 + 0] = bv.x; bias[o4 * 4 + 1] = bv.y;
      bias[o4 * 4 + 2] = bv.z; bias[o4 * 4 + 3] = bv.w;
    }
  }
#pragma unroll
  for (int q = 0; q < 4; ++q) {
    float* up = uvt + ((size_t)b * NPT + n0 + nq * 4 + q) * 384 + ob * 24;
#pragma unroll
    for (int o4 = 0; o4 < 6; ++o4) {
      float4 v;
      v.x = acc[q][o4 * 4 + 0] + bias[o4 * 4 + 0];
      v.y = acc[q][o4 * 4 + 1] + bias[o4 * 4 + 1];
      v.z = acc[q][o4 * 4 + 2] + bias[o4 * 4 + 2];
      v.w = acc[q][o4 * 4 + 3] + bias[o4 * 4 + 3];
      *(float4*)&up[o4 * 4] = v;
    }
  }
}

// ---------------- K5: agg_t[n][o] = relu(max_k (u[n][o] + v[idx[n][k]][o])) ------------
__global__ __launch_bounds__(256) void k_gather(const float* __restrict__ uvt,
                                                const int* __restrict__ nn_idx,
                                                float* __restrict__ aggt) {
  int bid = blockIdx.x;
  int b = bid & 7;      // XCD affinity for the per-batch v table
  int ng = bid >> 3;    // 0..783
  int wid = threadIdx.x >> 6, lane = threadIdx.x & 63;
  int n = ng * 4 + wid;
  if (lane >= 48) return;
  const float* base = uvt + (size_t)b * NPT * 384;
  const int* ip = nn_idx + ((size_t)b * NPT + n) * NK;
  float4 u = *(const float4*)&base[(size_t)n * 384 + lane * 4];
  float4 acc = make_float4(-1e30f, -1e30f, -1e30f, -1e30f);
#pragma unroll
  for (int k = 0; k < NK; ++k) {
    int j = ip[k];
    float4 v = *(const float4*)&base[(size_t)j * 384 + 192 + lane * 4];
    acc.x = fmaxf(acc.x, u.x + v.x);
    acc.y = fmaxf(acc.y, u.y + v.y);
    acc.z = fmaxf(acc.z, u.z + v.z);
    acc.w = fmaxf(acc.w, u.w + v.w);
  }
  float4 o;
  o.x = fmaxf(acc.x, 0.f); o.y = fmaxf(acc.y, 0.f);
  o.z = fmaxf(acc.z, 0.f); o.w = fmaxf(acc.w, 0.f);
  *(float4*)&aggt[((size_t)b * NPT + n) * 192 + lane * 4] = o;
}

// ---------------- K6: out = W2f @ agg + b2f + residual ---------------------------------
// 1-wave blocks, 16 n each. lane = (nq, ob16); thread owns 4 n x 6 o. K=192, 8 chunks.
__global__ __launch_bounds__(64, 2) void k_out(const float* __restrict__ aggt,
                                               const float* __restrict__ W2f,
                                               const float* __restrict__ b2f,
                                               const float* __restrict__ x,
                                               float* __restrict__ out) {
  int bid = blockIdx.x;      // 1568
  int b = bid & 7;
  int ng = bid >> 3;
  int n0 = ng * 16;
  int lane = threadIdx.x;
  int ob = lane & 15, nq = lane >> 4;

  __shared__ float w_lds[24 * OUT_WSTR];  // 9600 B
  __shared__ float a_lds[24 * 16];        // 1536 B

  float acc[4][6];
#pragma unroll
  for (int q = 0; q < 4; ++q)
#pragma unroll
    for (int oo = 0; oo < 6; ++oo) acc[q][oo] = 0.f;

  const float* ab = aggt + ((size_t)b * NPT + n0) * 192;

  for (int ch = 0; ch < 8; ++ch) {
    __syncthreads();
    {  // stage W2f chunk (24 c x 96 o) into [cc][100]
      const float* wsrc = W2f + ch * 24 * 96;
#pragma unroll
      for (int it = 0; it < 9; ++it) {
        int i = lane * 4 + it * 256;
        float4 v = *(const float4*)&wsrc[i];
        int cc = i / 96, o = i % 96;
        *(float4*)&w_lds[cc * OUT_WSTR + o] = v;
      }
      // stage agg chunk: [24 cc][16 n] (transpose from n-major rows)
#pragma unroll
      for (int it = 0; it < 2; ++it) {
        int i = lane + it * 64;
        if (i < 96) {
          int nn = i / 6, c4 = i % 6;
          float4 v = *(const float4*)&ab[(size_t)nn * 192 + ch * 24 + c4 * 4];
          a_lds[(c4 * 4 + 0) * 16 + nn] = v.x;
          a_lds[(c4 * 4 + 1) * 16 + nn] = v.y;
          a_lds[(c4 * 4 + 2) * 16 + nn] = v.z;
          a_lds[(c4 * 4 + 3) * 16 + nn] = v.w;
        }
      }
    }
    __syncthreads();
#pragma unroll
    for (int cc = 0; cc < 24; ++cc) {
      float4 a = *(const float4*)&a_lds[cc * 16 + nq * 4];
      const float* wp = &w_lds[cc * OUT_WSTR + ob * 6];
      float2 w01 = *(const float2*)&wp[0];
      float2 w23 = *(const float2*)&wp[2];
      float2 w45 = *(const float2*)&wp[4];
      float w[6] = {w01.x, w01.y, w23.x, w23.y, w45.x, w45.y};
#pragma unroll
      for (int oo = 0; oo < 6; ++oo) {
        acc[0][oo] = fmaf(w[oo], a.x, acc[0][oo]);
        acc[1][oo] = fmaf(w[oo], a.y, acc[1][oo]);
        acc[2][oo] = fmaf(w[oo], a.z, acc[2][oo]);
        acc[3][oo] = fmaf(w[oo], a.w, acc[3][oo]);
      }
    }
  }

  const float* xb = x + (size_t)b * NC * NPT;
  float* ob_out = out + (size_t)b * NC * NPT;
#pragma unroll
  for (int oo = 0; oo < 6; ++oo) {
    int o = ob * 6 + oo;
    float bb = b2f[o];
#pragma unroll
    for (int q = 0; q < 4; ++q) {
      int n = n0 + nq * 4 + q;
      ob_out[(size_t)o * NPT + n] = acc[q][oo] + bb + xb[(size_t)o * NPT + n];
    }
  }
}

extern "C" void kernel_launch(void* const* d_in, const int* in_sizes, int n_in,
                              void* d_out, int out_size, void* d_ws, size_t ws_size,
                              hipStream_t stream) {
  const float* x  = (const float*)d_in[0];
  const float* W1 = (const float*)d_in[1];
  const float* b1 = (const float*)d_in[2];
  const float* g1 = (const float*)d_in[3];
  const float* be1= (const float*)d_in[4];
  const float* m1 = (const float*)d_in[5];
  const float* v1 = (const float*)d_in[6];
  const float* Wg = (const float*)d_in[7];
  const float* bg = (const float*)d_in[8];
  const float* W2 = (const float*)d_in[9];
  const float* b2 = (const float*)d_in[10];
  const float* g2 = (const float*)d_in[11];
  const float* be2= (const float*)d_in[12];
  const float* m2 = (const float*)d_in[13];
  const float* v2 = (const float*)d_in[14];
  float* out = (float*)d_out;

  float* ws = (float*)d_ws;
  size_t off = 0;
  float* feat = ws + off; off += (size_t)NB * NC * NPT;             // 9.6 MB
  unsigned short* hiT = (unsigned short*)(ws + off); off += (size_t)NB * NPT * NC / 2;
  unsigned short* loT = (unsigned short*)(ws + off); off += (size_t)NB * NPT * NC / 2;
  float* uvt  = ws + off; off += (size_t)NB * NPT * 384;            // 38.5 MB
  float* aggt = ws + off; off += (size_t)NB * NPT * 192;            // 19.3 MB
  float* W1f  = ws + off; off += NC * NC;
  float* Wuv  = ws + off; off += NC * 2 * NC2;
  float* W2f  = ws + off; off += NC2 * NC;
  float* b1f  = ws + off; off += 128;
  float* b2f  = ws + off; off += 128;

  // Phase-disjoint overlays (unchanged from R7):
  float* fnT    = aggt;
  unsigned* pk  = (unsigned*)uvt;
  int* cand     = (int*)hiT;
  int* nn_idx   = (int*)loT;

  k_fuse<<<dim3(64), 256, 0, stream>>>(W1, b1, g1, be1, m1, v1, Wg, W2, b2, g2, be2, m2, v2,
                                       W1f, b1f, Wuv, W2f, b2f);
  k_feat<<<dim3(25, NB), 128, 0, stream>>>(x, W1f, b1f, feat, fnT, hiT, loT);
  k_knn<<<dim3(NB * 98 * 2), 256, 0, stream>>>(hiT, loT, pk);
  k_nnmerge<<<dim3((NB * NPT + 255) / 256), 256, 0, stream>>>(pk, cand);
  k_rescore<<<dim3(NB * NPT / 4), 256, 0, stream>>>(fnT, cand, nn_idx);
  k_uv<<<dim3(NB * 196), 64, 0, stream>>>(feat, Wuv, bg, uvt);
  k_gather<<<dim3(NB * NPT / 4), 256, 0, stream>>>(uvt, nn_idx, aggt);
  k_out<<<dim3(NB * 196), 64, 0, stream>>>(aggt, W2f, b2f, x, out);
}

// Round 9
// 304.781 us; speedup vs baseline: 2.5540x; 1.0318x over previous
//
#include <hip/hip_runtime.h>
#include <cstdint>

#define NB 8
#define NC 96
#define NC2 192
#define NPT 3136    // 56*56
#define NK 9
#define NLIST 16    // lists per row: 8 j-splits x 2 lane-halves
#define NDEP 9      // per-lane list depth (>= NK for superset guarantee)
#define NCAND 16    // pooled candidate count per row
#define NROWS (NB * NPT)
#define RST 104     // fnT row stride (96 fn + sq at [96] + pad)
#define UV_WSTR 292 // k_uv LDS per-ob stride
#define OUT_WSTR 100// k_out LDS cc stride
#define FT_WSTR 76  // k_feat LDS per-ob stride: 12cc*6oo + 4 pad (mod32=12 -> 2-way, free)
static constexpr float BN_EPS = 1e-5f;
typedef unsigned long long u64;
typedef float f32x16 __attribute__((ext_vector_type(16)));
typedef short short8 __attribute__((ext_vector_type(8)));

__device__ inline unsigned short f32_to_bf16_rne(float x) {
  unsigned u = __float_as_uint(x);
  unsigned r = (u + 0x7FFFu + ((u >> 16) & 1u)) >> 16;
  return (unsigned short)r;
}

__device__ inline unsigned score_to_key_exact(float s) {
  unsigned u = __float_as_uint(s);
  u ^= 0x80000000u | (unsigned)((int)u >> 31);  // monotone increasing map
  return ~u;                                    // descending score = ascending dist
}

// ---------------- K1: fold BN into weights, build fused weight layouts ----------------
// W1s: swizzled [ch8][ob16][cc12][oo6] for k_feat staging.
__global__ void k_fuse(const float* __restrict__ W1, const float* __restrict__ b1,
                       const float* __restrict__ g1, const float* __restrict__ be1,
                       const float* __restrict__ m1, const float* __restrict__ v1,
                       const float* __restrict__ Wg,
                       const float* __restrict__ W2, const float* __restrict__ b2,
                       const float* __restrict__ g2, const float* __restrict__ be2,
                       const float* __restrict__ m2, const float* __restrict__ v2,
                       float* __restrict__ W1s, float* __restrict__ b1f,
                       float* __restrict__ Wuv,
                       float* __restrict__ W2f, float* __restrict__ b2f) {
  int t = blockIdx.x * blockDim.x + threadIdx.x;
  int nth = gridDim.x * blockDim.x;
  for (int i = t; i < NC * NC; i += nth) {
    int ch = i / 1152, r = i % 1152;
    int ob = r / 72, r2 = r % 72;
    int cc = r2 / 6, oo = r2 % 6;
    int c = ch * 12 + cc, o = ob * 6 + oo;
    float inv = g1[o] / sqrtf(v1[o] + BN_EPS);
    W1s[i] = W1[o * NC + c] * inv;
  }
  for (int o = t; o < NC; o += nth) {
    float inv = g1[o] / sqrtf(v1[o] + BN_EPS);
    b1f[o] = b1[o] * inv + be1[o] - m1[o] * inv;
    float inv2v = g2[o] / sqrtf(v2[o] + BN_EPS);
    b2f[o] = b2[o] * inv2v + be2[o] - m2[o] * inv2v;
  }
  for (int i = t; i < NC * (2 * NC2); i += nth) {
    int c = i / (2 * NC2), o4 = i % (2 * NC2);
    float val;
    if (o4 < NC2) val = Wg[o4 * NC2 + c] - Wg[o4 * NC2 + NC + c];
    else          val = Wg[(o4 - NC2) * NC2 + NC + c];
    Wuv[i] = val;
  }
  for (int i = t; i < NC2 * NC; i += nth) {
    int c = i / NC, o = i % NC;
    float inv = g2[o] / sqrtf(v2[o] + BN_EPS);
    W2f[i] = W2[o * NC2 + c] * inv;
  }
}

// ------- K2: feat = BN(W1 x + b1); fnT = f32 fn rows (+sq); hiT/loT = bf16 split -------
// 1-wave blocks, 16 n. lane = (nq = lane>>4, ob = lane&15); thread owns 4n x 6o.
// Per-(n,o) accumulation order identical to prior rounds (c ascending, init b1f).
__global__ __launch_bounds__(64, 4) void k_feat(const float* __restrict__ x,
                                                const float* __restrict__ W1s,
                                                const float* __restrict__ b1f,
                                                float* __restrict__ feat,
                                                float* __restrict__ fnT,
                                                unsigned short* __restrict__ hiT,
                                                unsigned short* __restrict__ loT) {
  int bid = blockIdx.x;      // 1568
  int b = bid & 7;
  int ng = bid >> 3;         // 0..195
  int n0 = ng * 16;
  int lane = threadIdx.x;
  int ob = lane & 15, nq = lane >> 4;

  __shared__ float w_lds[16 * FT_WSTR];  // 4864 B
  __shared__ float f_lds[12 * 16];       // 768 B

  const float* xb = x + (size_t)b * NC * NPT;
  float acc[4][6];
#pragma unroll
  for (int oo = 0; oo < 6; ++oo) {
    float bv = b1f[ob * 6 + oo];
#pragma unroll
    for (int q = 0; q < 4; ++q) acc[q][oo] = bv;
  }

  for (int ch = 0; ch < 8; ++ch) {
    __syncthreads();
    {  // stage W chunk (1152 contiguous floats) with pad insert
      const float* wsrc = W1s + ch * 1152;
#pragma unroll
      for (int it = 0; it < 5; ++it) {
        int i = it * 256 + lane * 4;
        if (it < 4 || lane < 32) {
          float4 v = *(const float4*)&wsrc[i];
          *(float4*)&w_lds[(i / 72) * FT_WSTR + (i % 72)] = v;
        }
      }
      // stage x chunk (12 c x 16 n)
#pragma unroll
      for (int it = 0; it < 3; ++it) {
        int i = it * 64 + lane;
        f_lds[i] = xb[(size_t)(ch * 12 + (i >> 4)) * NPT + n0 + (i & 15)];
      }
    }
    __syncthreads();
#pragma unroll
    for (int cc = 0; cc < 12; ++cc) {
      float4 a = *(const float4*)&f_lds[cc * 16 + nq * 4];
      const float* wp = &w_lds[ob * FT_WSTR + cc * 6];
      float2 w01 = *(const float2*)&wp[0];
      float2 w23 = *(const float2*)&wp[2];
      float2 w45 = *(const float2*)&wp[4];
      float w[6] = {w01.x, w01.y, w23.x, w23.y, w45.x, w45.y};
#pragma unroll
      for (int oo = 0; oo < 6; ++oo) {
        acc[0][oo] = fmaf(w[oo], a.x, acc[0][oo]);
        acc[1][oo] = fmaf(w[oo], a.y, acc[1][oo]);
        acc[2][oo] = fmaf(w[oo], a.z, acc[2][oo]);
        acc[3][oo] = fmaf(w[oo], a.w, acc[3][oo]);
      }
    }
  }

  // norm reduce across the 16 ob-lanes of each nq group
  float sq[4];
#pragma unroll
  for (int q = 0; q < 4; ++q) {
    float s = 0.f;
#pragma unroll
    for (int oo = 0; oo < 6; ++oo) s += acc[q][oo] * acc[q][oo];
    sq[q] = s;
  }
#pragma unroll
  for (int m = 1; m < 16; m <<= 1) {
#pragma unroll
    for (int q = 0; q < 4; ++q) sq[q] += __shfl_xor(sq[q], m);
  }

  float* fb = feat + (size_t)b * NC * NPT;
  float vnn[4][6];
  float sqn[4];
#pragma unroll
  for (int q = 0; q < 4; ++q) {
    float den = fmaxf(sqrtf(sq[q]), 1e-12f);
    float s = 0.f;
#pragma unroll
    for (int oo = 0; oo < 6; ++oo) {
      float v = acc[q][oo] / den;
      vnn[q][oo] = v;
      s += v * v;
    }
    sqn[q] = s;
  }
#pragma unroll
  for (int m = 1; m < 16; m <<= 1) {
#pragma unroll
    for (int q = 0; q < 4; ++q) sqn[q] += __shfl_xor(sqn[q], m);
  }

#pragma unroll
  for (int q = 0; q < 4; ++q) {
    int n = n0 + nq * 4 + q;
#pragma unroll
    for (int oo = 0; oo < 6; ++oo)
      fb[(size_t)(ob * 6 + oo) * NPT + n] = acc[q][oo];
    float* fr = fnT + ((size_t)b * NPT + n) * RST;
#pragma unroll
    for (int oo = 0; oo < 6; ++oo) fr[ob * 6 + oo] = vnn[q][oo];
    if (ob == 0) fr[96] = sqn[q];
    unsigned short* hr = hiT + ((size_t)b * NPT + n) * NC + ob * 6;
    unsigned short* lr = loT + ((size_t)b * NPT + n) * NC + ob * 6;
#pragma unroll
    for (int p2 = 0; p2 < 3; ++p2) {
      float v0 = vnn[q][p2 * 2], v1 = vnn[q][p2 * 2 + 1];
      unsigned short h0 = f32_to_bf16_rne(v0);
      unsigned short h1 = f32_to_bf16_rne(v1);
      float hv0 = __uint_as_float(((unsigned)h0) << 16);
      float hv1 = __uint_as_float(((unsigned)h1) << 16);
      unsigned short l0 = f32_to_bf16_rne(v0 - hv0);
      unsigned short l1 = f32_to_bf16_rne(v1 - hv1);
      *(unsigned*)&hr[p2 * 2] = (unsigned)h0 | ((unsigned)h1 << 16);
      *(unsigned*)&lr[p2 * 2] = (unsigned)l0 | ((unsigned)l1 << 16);
    }
  }
}

// ---------------- K3: KNN candidate gen via compensated bf16 MFMA ----------------------
// Selection: parallel rank-insert network — kk[s] = med3(kk[s-1], kk[s], e) (all from
// old state, no serial chain), kk[0] = max(kk[0], e). Keys are positive-float packed
// (bits(score+2) & ~0x1FF) | rel_j, so f32 med3/max == u32 ordering.
__global__ __launch_bounds__(256, 4) void k_knn(const unsigned short* __restrict__ hiT,
                                                const unsigned short* __restrict__ loT,
                                                unsigned* __restrict__ pk) {
  int bid = blockIdx.x;
  int b = bid & 7;            // XCD affinity
  int r2 = bid >> 3;          // 0..195
  int iblk = r2 % 98;
  int jp = r2 / 98;           // 0..1
  int wq = threadIdx.x >> 6;  // 0..3
  int jsplit = jp * 4 + wq;   // 0..7
  int lane = threadIdx.x & 63;
  int col = lane & 31;
  int half = lane >> 5;
  int i = iblk * 32 + col;

  const unsigned short* hb = hiT + (size_t)b * NPT * NC;
  const unsigned short* lb = loT + (size_t)b * NPT * NC;

  short8 Bh[6], Bl[6];
  {
    const unsigned short* ih = hb + (size_t)i * NC + half * 8;
    const unsigned short* il = lb + (size_t)i * NC + half * 8;
#pragma unroll
    for (int ch = 0; ch < 6; ++ch) {
      Bh[ch] = *(const short8*)(ih + ch * 16);
      Bl[ch] = *(const short8*)(il + ch * 16);
    }
  }

  float kk[NDEP];
#pragma unroll
  for (int k = 0; k < NDEP; ++k) kk[k] = 0.0f;   // 0.0 < any real key (+1..3)

  int t0 = (98 * jsplit) >> 3, t1 = (98 * (jsplit + 1)) >> 3;
  int jbase = t0 * 32;
  for (int t = t0; t < t1; ++t) {
    int j0 = t * 32;
    const unsigned short* ah = hb + (size_t)(j0 + col) * NC + half * 8;
    const unsigned short* al = lb + (size_t)(j0 + col) * NC + half * 8;
    f32x16 acc;
#pragma unroll
    for (int r = 0; r < 16; ++r) acc[r] = 0.f;
    {
      short8 A[6];
#pragma unroll
      for (int ch = 0; ch < 6; ++ch) A[ch] = *(const short8*)(ah + ch * 16);
#pragma unroll
      for (int ch = 0; ch < 6; ++ch)
        acc = __builtin_amdgcn_mfma_f32_32x32x16_bf16(A[ch], Bh[ch], acc, 0, 0, 0);
#pragma unroll
      for (int ch = 0; ch < 6; ++ch)
        acc = __builtin_amdgcn_mfma_f32_32x32x16_bf16(A[ch], Bl[ch], acc, 0, 0, 0);
    }
    {
      short8 A[6];
#pragma unroll
      for (int ch = 0; ch < 6; ++ch) A[ch] = *(const short8*)(al + ch * 16);
#pragma unroll
      for (int ch = 0; ch < 6; ++ch)
        acc = __builtin_amdgcn_mfma_f32_32x32x16_bf16(A[ch], Bh[ch], acc, 0, 0, 0);
    }
    unsigned relbase = (unsigned)(j0 - jbase + 4 * half);
#pragma unroll
    for (int r = 0; r < 16; ++r) {
      unsigned kb = __float_as_uint(acc[r] + 2.0f);
      unsigned keyu = (kb & 0xFFFFFE00u) | (relbase + (unsigned)((r & 3) + 8 * (r >> 2)));
      float e = __uint_as_float(keyu);
#pragma unroll
      for (int s = NDEP - 1; s > 0; --s)
        kk[s] = __builtin_amdgcn_fmed3f(kk[s - 1], kk[s], e);
      kk[0] = fmaxf(kk[0], e);
    }
  }

  // coalesced store: pk[(L*NDEP + k)*NROWS + row]
  unsigned* op = pk + (size_t)(jsplit * 2 + half) * NDEP * NROWS + ((size_t)b * NPT + i);
#pragma unroll
  for (int k = 0; k < NDEP; ++k) op[(size_t)k * NROWS] = __float_as_uint(kk[k]);
}

// ---------------- K3b: merge NLIST sorted 9-lists per row -> top-16 candidate set ------
__global__ __launch_bounds__(256) void k_nnmerge(const unsigned* __restrict__ pk,
                                                 int* __restrict__ cand) {
  int rg = blockIdx.x * 256 + threadIdx.x;
  if (rg >= NROWS) return;
  const unsigned* p = pk + rg;
  u64 kc[NCAND];
#pragma unroll
  for (int k = 0; k < NCAND; ++k) kc[k] = 0ull;
  for (int s = 0; s < NLIST; ++s) {
#pragma unroll
    for (int k = 0; k < NDEP; ++k) {
      u64 e = ((u64)p[(size_t)(s * NDEP + k) * NROWS] << 4) | (unsigned)s;
      if (e <= kc[NCAND - 1]) break;   // sorted desc source: rest can't qualify
      kc[NCAND - 1] = e;
#pragma unroll
      for (int q = NCAND - 1; q > 0; --q) {
        u64 xx = kc[q - 1], yy = kc[q];
        bool sw = yy > xx;
        kc[q - 1] = sw ? yy : xx;
        kc[q]     = sw ? xx : yy;
      }
    }
  }
  int* op = cand + (size_t)rg * NCAND;
#pragma unroll
  for (int k = 0; k < NCAND; ++k) {
    u64 e = kc[k];
    int s = (int)(e & 0xF);
    int rel = (int)((e >> 4) & 0x1FF);
    int jb = (((98 * (s >> 1)) >> 3) << 5);
    op[k] = jb + rel;
  }
}

// ---------------- K3c: f32 rescore of 16 candidates -> exact top-9 ---------------------
__global__ __launch_bounds__(256) void k_rescore(const float* __restrict__ fnT,
                                                 const int* __restrict__ cand,
                                                 int* __restrict__ nn_idx) {
  __shared__ u64 kl[4][NCAND];
  int wid = threadIdx.x >> 6, lane = threadIdx.x & 63;
  int row = blockIdx.x * 4 + wid;            // 0..25087 (grid exact)
  int b = row / NPT;
  int c = lane >> 2, sub = lane & 3;
  int j = cand[(size_t)row * NCAND + c];
  const float* fi = fnT + (size_t)row * RST + sub * 24;
  const float* fj = fnT + (size_t)(b * NPT + j) * RST + sub * 24;
  float p = 0.f;
#pragma unroll
  for (int c4 = 0; c4 < 6; ++c4) {
    float4 a = *(const float4*)&fi[c4 * 4];
    float4 v = *(const float4*)&fj[c4 * 4];
    p = fmaf(a.x, v.x, p); p = fmaf(a.y, v.y, p);
    p = fmaf(a.z, v.z, p); p = fmaf(a.w, v.w, p);
  }
  p += __shfl_xor(p, 1);
  p += __shfl_xor(p, 2);
  if (sub == 0) {
    float sqj = fnT[(size_t)(b * NPT + j) * RST + 96];
    float score = fmaf(-0.5f, sqj, p);
    kl[wid][c] = ((u64)score_to_key_exact(score) << 32) | (unsigned)j;
  }
  __syncthreads();
  if (lane == 0) {
    u64 k9[NK];
#pragma unroll
    for (int k = 0; k < NK; ++k) k9[k] = ~0ull;
#pragma unroll
    for (int t = 0; t < NCAND; ++t) {
      u64 key = kl[wid][t];
      if (key < k9[NK - 1]) {
        k9[NK - 1] = key;
#pragma unroll
        for (int q = NK - 1; q > 0; --q) {
          u64 xx = k9[q - 1], yy = k9[q];
          bool sw = yy < xx;
          k9[q - 1] = sw ? yy : xx;
          k9[q]     = sw ? xx : yy;
        }
      }
    }
    int* op = nn_idx + (size_t)row * NK;
#pragma unroll
    for (int k = 0; k < NK; ++k) op[k] = (int)(unsigned)(k9[k] & 0xFFFFFFFFu);
  }
}

// ---------------- K4: uvt = [A;B] @ feat (+bg on u-half), transposed store -------------
__global__ __launch_bounds__(64, 2) void k_uv(const float* __restrict__ feat,
                                              const float* __restrict__ Wuv,
                                              const float* __restrict__ bg,
                                              float* __restrict__ uvt) {
  int bid = blockIdx.x;      // 1568
  int b = bid & 7;
  int ng = bid >> 3;         // 0..195
  int n0 = ng * 16;
  int lane = threadIdx.x;
  int ob = lane & 15, nq = lane >> 4;

  __shared__ float w_lds[16 * UV_WSTR];   // 18688 B
  __shared__ float f_lds[12 * 16];        // 768 B

  const float* fb = feat + (size_t)b * NC * NPT;
  float acc[4][24];
#pragma unroll
  for (int q = 0; q < 4; ++q)
#pragma unroll
    for (int oo = 0; oo < 24; ++oo) acc[q][oo] = 0.f;

  for (int ch = 0; ch < 8; ++ch) {
    __syncthreads();
    {
      const float* wsrc = Wuv + ch * 12 * 384;
#pragma unroll
      for (int it = 0; it < 18; ++it) {
        int i = lane * 4 + it * 256;
        float4 v = *(const float4*)&wsrc[i];
        int cc = i / 384, o = i % 384;
        *(float4*)&w_lds[(o / 24) * UV_WSTR + cc * 24 + (o % 24)] = v;
      }
#pragma unroll
      for (int it = 0; it < 3; ++it) {
        int i = lane + it * 64;
        int cc = i >> 4, nn = i & 15;
        f_lds[i] = fb[(size_t)(ch * 12 + cc) * NPT + n0 + nn];
      }
    }
    __syncthreads();
#pragma unroll
    for (int cc = 0; cc < 12; ++cc) {
      float4 a = *(const float4*)&f_lds[cc * 16 + nq * 4];
      const float* wp = &w_lds[ob * UV_WSTR + cc * 24];
#pragma unroll
      for (int o4 = 0; o4 < 6; ++o4) {
        float4 w = *(const float4*)&wp[o4 * 4];
#pragma unroll
        for (int e = 0; e < 4; ++e) {
          float we = ((const float*)&w)[e];
          acc[0][o4 * 4 + e] = fmaf(we, a.x, acc[0][o4 * 4 + e]);
          acc[1][o4 * 4 + e] = fmaf(we, a.y, acc[1][o4 * 4 + e]);
          acc[2][o4 * 4 + e] = fmaf(we, a.z, acc[2][o4 * 4 + e]);
          acc[3][o4 * 4 + e] = fmaf(we, a.w, acc[3][o4 * 4 + e]);
        }
      }
    }
  }

  float bias[24];
#pragma unroll
  for (int oo = 0; oo < 24; ++oo) bias[oo] = 0.f;
  if (ob < 8) {
#pragma unroll
    for (int o4 = 0; o4 < 6; ++o4) {
      float4 bv = *(const float4*)&bg[ob * 24 + o4 * 4];
      bias[o4 * 4 + 0] = bv.x; bias[o4 * 4 + 1] = bv.y;
      bias[o4 * 4 + 2] = bv.z; bias[o4 * 4 + 3] = bv.w;
    }
  }
#pragma unroll
  for (int q = 0; q < 4; ++q) {
    float* up = uvt + ((size_t)b * NPT + n0 + nq * 4 + q) * 384 + ob * 24;
#pragma unroll
    for (int o4 = 0; o4 < 6; ++o4) {
      float4 v;
      v.x = acc[q][o4 * 4 + 0] + bias[o4 * 4 + 0];
      v.y = acc[q][o4 * 4 + 1] + bias[o4 * 4 + 1];
      v.z = acc[q][o4 * 4 + 2] + bias[o4 * 4 + 2];
      v.w = acc[q][o4 * 4 + 3] + bias[o4 * 4 + 3];
      *(float4*)&up[o4 * 4] = v;
    }
  }
}

// ---------------- K5: agg_t[n][o] = relu(max_k (u[n][o] + v[idx[n][k]][o])) ------------
__global__ __launch_bounds__(256) void k_gather(const float* __restrict__ uvt,
                                                const int* __restrict__ nn_idx,
                                                float* __restrict__ aggt) {
  int bid = blockIdx.x;
  int b = bid & 7;
  int ng = bid >> 3;    // 0..783
  int wid = threadIdx.x >> 6, lane = threadIdx.x & 63;
  int n = ng * 4 + wid;
  if (lane >= 48) return;
  const float* base = uvt + (size_t)b * NPT * 384;
  const int* ip = nn_idx + ((size_t)b * NPT + n) * NK;
  float4 u = *(const float4*)&base[(size_t)n * 384 + lane * 4];
  float4 acc = make_float4(-1e30f, -1e30f, -1e30f, -1e30f);
#pragma unroll
  for (int k = 0; k < NK; ++k) {
    int j = ip[k];
    float4 v = *(const float4*)&base[(size_t)j * 384 + 192 + lane * 4];
    acc.x = fmaxf(acc.x, u.x + v.x);
    acc.y = fmaxf(acc.y, u.y + v.y);
    acc.z = fmaxf(acc.z, u.z + v.z);
    acc.w = fmaxf(acc.w, u.w + v.w);
  }
  float4 o;
  o.x = fmaxf(acc.x, 0.f); o.y = fmaxf(acc.y, 0.f);
  o.z = fmaxf(acc.z, 0.f); o.w = fmaxf(acc.w, 0.f);
  *(float4*)&aggt[((size_t)b * NPT + n) * 192 + lane * 4] = o;
}

// ---------------- K6: out = W2f @ agg + b2f + residual ---------------------------------
__global__ __launch_bounds__(64, 2) void k_out(const float* __restrict__ aggt,
                                               const float* __restrict__ W2f,
                                               const float* __restrict__ b2f,
                                               const float* __restrict__ x,
                                               float* __restrict__ out) {
  int bid = blockIdx.x;      // 1568
  int b = bid & 7;
  int ng = bid >> 3;
  int n0 = ng * 16;
  int lane = threadIdx.x;
  int ob = lane & 15, nq = lane >> 4;

  __shared__ float w_lds[24 * OUT_WSTR];  // 9600 B
  __shared__ float a_lds[24 * 16];        // 1536 B

  float acc[4][6];
#pragma unroll
  for (int q = 0; q < 4; ++q)
#pragma unroll
    for (int oo = 0; oo < 6; ++oo) acc[q][oo] = 0.f;

  const float* ab = aggt + ((size_t)b * NPT + n0) * 192;

  for (int ch = 0; ch < 8; ++ch) {
    __syncthreads();
    {
      const float* wsrc = W2f + ch * 24 * 96;
#pragma unroll
      for (int it = 0; it < 9; ++it) {
        int i = lane * 4 + it * 256;
        float4 v = *(const float4*)&wsrc[i];
        int cc = i / 96, o = i % 96;
        *(float4*)&w_lds[cc * OUT_WSTR + o] = v;
      }
#pragma unroll
      for (int it = 0; it < 2; ++it) {
        int i = lane + it * 64;
        if (i < 96) {
          int nn = i / 6, c4 = i % 6;
          float4 v = *(const float4*)&ab[(size_t)nn * 192 + ch * 24 + c4 * 4];
          a_lds[(c4 * 4 + 0) * 16 + nn] = v.x;
          a_lds[(c4 * 4 + 1) * 16 + nn] = v.y;
          a_lds[(c4 * 4 + 2) * 16 + nn] = v.z;
          a_lds[(c4 * 4 + 3) * 16 + nn] = v.w;
        }
      }
    }
    __syncthreads();
#pragma unroll
    for (int cc = 0; cc < 24; ++cc) {
      float4 a = *(const float4*)&a_lds[cc * 16 + nq * 4];
      const float* wp = &w_lds[cc * OUT_WSTR + ob * 6];
      float2 w01 = *(const float2*)&wp[0];
      float2 w23 = *(const float2*)&wp[2];
      float2 w45 = *(const float2*)&wp[4];
      float w[6] = {w01.x, w01.y, w23.x, w23.y, w45.x, w45.y};
#pragma unroll
      for (int oo = 0; oo < 6; ++oo) {
        acc[0][oo] = fmaf(w[oo], a.x, acc[0][oo]);
        acc[1][oo] = fmaf(w[oo], a.y, acc[1][oo]);
        acc[2][oo] = fmaf(w[oo], a.z, acc[2][oo]);
        acc[3][oo] = fmaf(w[oo], a.w, acc[3][oo]);
      }
    }
  }

  const float* xb = x + (size_t)b * NC * NPT;
  float* ob_out = out + (size_t)b * NC * NPT;
#pragma unroll
  for (int oo = 0; oo < 6; ++oo) {
    int o = ob * 6 + oo;
    float bb = b2f[o];
#pragma unroll
    for (int q = 0; q < 4; ++q) {
      int n = n0 + nq * 4 + q;
      ob_out[(size_t)o * NPT + n] = acc[q][oo] + bb + xb[(size_t)o * NPT + n];
    }
  }
}

extern "C" void kernel_launch(void* const* d_in, const int* in_sizes, int n_in,
                              void* d_out, int out_size, void* d_ws, size_t ws_size,
                              hipStream_t stream) {
  const float* x  = (const float*)d_in[0];
  const float* W1 = (const float*)d_in[1];
  const float* b1 = (const float*)d_in[2];
  const float* g1 = (const float*)d_in[3];
  const float* be1= (const float*)d_in[4];
  const float* m1 = (const float*)d_in[5];
  const float* v1 = (const float*)d_in[6];
  const float* Wg = (const float*)d_in[7];
  const float* bg = (const float*)d_in[8];
  const float* W2 = (const float*)d_in[9];
  const float* b2 = (const float*)d_in[10];
  const float* g2 = (const float*)d_in[11];
  const float* be2= (const float*)d_in[12];
  const float* m2 = (const float*)d_in[13];
  const float* v2 = (const float*)d_in[14];
  float* out = (float*)d_out;

  float* ws = (float*)d_ws;
  size_t off = 0;
  float* feat = ws + off; off += (size_t)NB * NC * NPT;             // 9.6 MB
  unsigned short* hiT = (unsigned short*)(ws + off); off += (size_t)NB * NPT * NC / 2;
  unsigned short* loT = (unsigned short*)(ws + off); off += (size_t)NB * NPT * NC / 2;
  float* uvt  = ws + off; off += (size_t)NB * NPT * 384;            // 38.5 MB
  float* aggt = ws + off; off += (size_t)NB * NPT * 192;            // 19.3 MB
  float* W1s  = ws + off; off += NC * NC;
  float* Wuv  = ws + off; off += NC * 2 * NC2;
  float* W2f  = ws + off; off += NC2 * NC;
  float* b1f  = ws + off; off += 128;
  float* b2f  = ws + off; off += 128;

  // Phase-disjoint overlays (unchanged):
  float* fnT    = aggt;
  unsigned* pk  = (unsigned*)uvt;   // 14.4 MB, [list][dep][row] coalesced layout
  int* cand     = (int*)hiT;
  int* nn_idx   = (int*)loT;

  k_fuse<<<dim3(64), 256, 0, stream>>>(W1, b1, g1, be1, m1, v1, Wg, W2, b2, g2, be2, m2, v2,
                                       W1s, b1f, Wuv, W2f, b2f);
  k_feat<<<dim3(NB * 196), 64, 0, stream>>>(x, W1s, b1f, feat, fnT, hiT, loT);
  k_knn<<<dim3(NB * 98 * 2), 256, 0, stream>>>(hiT, loT, pk);
  k_nnmerge<<<dim3((NROWS + 255) / 256), 256, 0, stream>>>(pk, cand);
  k_rescore<<<dim3(NROWS / 4), 256, 0, stream>>>(fnT, cand, nn_idx);
  k_uv<<<dim3(NB * 196), 64, 0, stream>>>(feat, Wuv, bg, uvt);
  k_gather<<<dim3(NB * NPT / 4), 256, 0, stream>>>(uvt, nn_idx, aggt);
  k_out<<<dim3(NB * 196), 64, 0, stream>>>(aggt, W2f, b2f, x, out);
}